// Round 3
// baseline (358.141 us; speedup 1.0000x reference)
//
#include <hip/hip_runtime.h>
#include <hip/hip_bf16.h>

// Transformer block: B=32 T=512 C=512 H=8 D=64
// Round 7: all four GEMMs -> counted-vmcnt phase-pipelined kernel (T3+T4+T5):
//  BM=256 BN=128 BK=64, 512 thr / 8 waves, LDS 128 KB dynamic:
//  A 3 slots (distance-2 prefetch, HBM-latency activations),
//  B 2 slots (distance-1, L2-resident weights).
//  2 phases per K-tile, raw s_barrier (+sched_barrier fences), setprio around
//  MFMA, ONE counted s_waitcnt vmcnt(4) per K-tile (never 0 mid-loop):
//    issue order per tile u: SB(u+1)@P0 (2 loads), SA(u+2)@P1 (4 loads);
//    at P1 vmcnt(4) completes A(u+1)+B(u+1), leaves A(u+2) in flight.
// Attention/LN/transpose unchanged from round 6.

#define B_  32
#define T_  512
#define C_  512
#define H_  8
#define D_  64
#define BT  (B_*T_)      // 16384 rows
#define CF  2048         // 4*C

typedef __hip_bfloat16 bf16;
typedef __attribute__((ext_vector_type(8))) short bf16x8;   // 8 bf16 (4 VGPRs)
typedef __attribute__((ext_vector_type(4))) float f32x4;
typedef __attribute__((ext_vector_type(4))) short short4v;

__device__ __forceinline__ float bf2f(bf16 x) { return __bfloat162float(x); }
__device__ __forceinline__ bf16  f2bf(float x){ return __float2bfloat16(x); }
__device__ __forceinline__ short f2bf_bits(float f){
    bf16 h = __float2bfloat16(f);
    return *reinterpret_cast<short*>(&h);
}
__device__ __forceinline__ float bfbits2f(short s){
    unsigned u = ((unsigned)(unsigned short)s) << 16;
    return __uint_as_float(u);
}

#define AS_G __attribute__((address_space(1)))
#define AS_L __attribute__((address_space(3)))

#define SCHED_FENCE() __builtin_amdgcn_sched_barrier(0)

// ---------------- All weight transposes in one launch ------------------------
__global__ __launch_bounds__(256) void transpose_all(const float* __restrict__ wq,
                                                     const float* __restrict__ wk,
                                                     const float* __restrict__ wv,
                                                     const float* __restrict__ wproj,
                                                     const float* __restrict__ w1,
                                                     const float* __restrict__ w2,
                                                     bf16* __restrict__ wt)
{
    const int t = blockIdx.x;
    const float* src; int K, Nn, k0, n0; size_t dstoff;
    if (t < 192) {
        const int which = t / 64, w = t % 64, hh = w >> 3, kt = w & 7;
        src = (which == 0 ? wq : which == 1 ? wk : wv) + (size_t)hh * 512 * 64;
        K = 512; Nn = 64; k0 = kt * 64; n0 = 0;
        dstoff = (size_t)(which * 512 + hh * 64) * 512;
    } else if (t < 256) {
        const int i = t - 192;
        src = wproj; K = 512; Nn = 512; n0 = (i & 7) * 64; k0 = (i >> 3) * 64;
        dstoff = (size_t)1536 * 512;
    } else if (t < 512) {
        const int i = t - 256;
        src = w1; K = 512; Nn = 2048; n0 = (i & 31) * 64; k0 = (i >> 5) * 64;
        dstoff = (size_t)2048 * 512;
    } else {
        const int i = t - 512;
        src = w2; K = 2048; Nn = 512; n0 = (i & 7) * 64; k0 = (i >> 3) * 64;
        dstoff = (size_t)2048 * 512 + (size_t)2048 * 512;
    }

    __shared__ float tl[64][65];
    const int tid = threadIdx.x;
    #pragma unroll
    for (int j = 0; j < 16; ++j) {
        const int e = j * 256 + tid, r = e >> 6, c = e & 63;
        tl[r][c] = src[(size_t)(k0 + r) * Nn + n0 + c];
    }
    __syncthreads();
    #pragma unroll
    for (int j = 0; j < 16; ++j) {
        const int e = j * 256 + tid, n = e >> 6, kk = e & 63;
        wt[dstoff + (size_t)(n0 + n) * K + k0 + kk] = f2bf(tl[kk][n]);
    }
}

// ---------------- LayerNorm: one block per row (C=512), 256 threads ----------
__global__ __launch_bounds__(256) void ln_kernel(const float* __restrict__ x,
                                                 const float* __restrict__ g,
                                                 const float* __restrict__ b,
                                                 bf16* __restrict__ out)
{
    const int row = blockIdx.x;
    const int tid = threadIdx.x;
    const float* xr = x + (size_t)row * C_;
    float v0 = xr[tid], v1 = xr[tid + 256];

    __shared__ float red[4];

    float s = v0 + v1;
    #pragma unroll
    for (int off = 32; off > 0; off >>= 1) s += __shfl_down(s, off, 64);
    if ((tid & 63) == 0) red[tid >> 6] = s;
    __syncthreads();
    const float mean = (red[0] + red[1] + red[2] + red[3]) * (1.0f / C_);
    __syncthreads();

    float d0 = v0 - mean, d1 = v1 - mean;
    float vs = d0 * d0 + d1 * d1;
    #pragma unroll
    for (int off = 32; off > 0; off >>= 1) vs += __shfl_down(vs, off, 64);
    if ((tid & 63) == 0) red[tid >> 6] = vs;
    __syncthreads();
    const float var  = (red[0] + red[1] + red[2] + red[3]) * (1.0f / C_);
    const float rstd = rsqrtf(var + 1e-5f);

    bf16* orow = out + (size_t)row * C_;
    orow[tid]       = f2bf(d0 * rstd * g[tid]       + b[tid]);
    orow[tid + 256] = f2bf(d1 * rstd * g[tid + 256] + b[tid + 256]);
}

// ---------------- MFMA GEMM, counted-vmcnt pipeline --------------------------
// C[M,N] = A[M,K](bf16) * Bt[N,K](bf16)^T.  BM=256 BN=128 BK=64.
// 512 threads = 8 waves: wm=wid>>2 (2 M-halves of 128 rows), wn=wid&3 (4 N
// strips of 32 cols). Per-wave out 128x32 = acc[8][2] f32x4 (C^T layout).
// LDS (dynamic 128 KB): A slots[3] 256x64, B slots[2] 128x64; 16B chunks
// XOR-8 swizzled (phys = chunk ^ (row&7)), staged linearly via
// global_load_lds width 16 with pre-swizzled global source.
// Schedule per K-tile u (2 phases, raw barriers, no vmcnt(0) mid-loop):
//  P0: ds_read B(u) 4x + A(u) qm0 8x; issue SB(u+1) [2 loads];
//      bar; setprio1; 16 MFMA (rows 0-63); setprio0; bar
//  P1: ds_read A(u) qm1 8x; issue SA(u+2) [4 loads];
//      vmcnt(4)  (completes A(u+1)+B(u+1), leaves A(u+2) in flight);
//      bar; setprio1; 16 MFMA (rows 64-127); setprio0; bar
// Safety: reads of tile u are only issued after the barrier that followed
// tile u-1's vmcnt -> staged data visible across waves. Slot rotation: A
// slot (u+2)%3 was last read at tile u-1 (barrier-separated); B slot
// (u+2)&1 = u&1 last read at tile u P0.
template<bool QKV, bool RELU, bool OUT_BF16>
__global__ __launch_bounds__(512, 2) void gemm8(const bf16* __restrict__ A,
                                                const bf16* __restrict__ Bt,
                                                const float* __restrict__ bias,
                                                const float* __restrict__ res,
                                                void* __restrict__ outp,
                                                int N, int K)
{
    extern __shared__ char smem[];
    bf16* const Asl = (bf16*)smem;                        // 3 x 256x64 (96 KB)
    bf16* const Bsl = (bf16*)(smem + 3 * 256 * 64 * 2);   // 2 x 128x64 (32 KB)

    const int tid  = threadIdx.x;
    const int lane = tid & 63, wid = tid >> 6;
    const int l16  = lane & 15, quad = lane >> 4;
    const int wm   = wid >> 2, wn = wid & 3;

    const int gridx = gridDim.x;
    const int nwg = gridx * gridDim.y;
    int bid = blockIdx.y * gridx + blockIdx.x;
    bid = (bid & 7) * (nwg >> 3) + (bid >> 3);            // bijective XCD swizzle
    const int tn = (bid % gridx) * 128;
    const int tm = (bid / gridx) * 256;
    const bool vblk = QKV && (tn >= 1024);
    const int NT = K >> 6;

    f32x4 acc[8][2];
    #pragma unroll
    for (int i = 0; i < 8; ++i)
        #pragma unroll
        for (int j = 0; j < 2; ++j) acc[i][j] = (f32x4){0.f, 0.f, 0.f, 0.f};

    // stage A K-tile u into slot s: 4 loads/thread (256 rows x 64 k)
    auto SA = [&](int s, int u) {
        bf16* dst = Asl + s * (256 * 64);
        const int k0 = u * 64;
        #pragma unroll
        for (int j = 0; j < 4; ++j) {
            const int g = j * 512 + tid;
            const int row = g >> 3, phys = g & 7;
            const int c = phys ^ (row & 7);
            __builtin_amdgcn_global_load_lds((const AS_G void*)(A + (size_t)(tm + row) * K + k0 + c * 8),
                                             (AS_L void*)(dst + (size_t)g * 8), 16, 0, 0);
        }
    };
    // stage B K-tile u into slot s: 2 loads/thread (128 rows x 64 k)
    auto SB = [&](int s, int u) {
        bf16* dst = Bsl + s * (128 * 64);
        const int k0 = u * 64;
        #pragma unroll
        for (int j = 0; j < 2; ++j) {
            const int g = j * 512 + tid;
            const int row = g >> 3, phys = g & 7;
            const int c = phys ^ (row & 7);
            __builtin_amdgcn_global_load_lds((const AS_G void*)(Bt + (size_t)(tn + row) * K + k0 + c * 8),
                                             (AS_L void*)(dst + (size_t)g * 8), 16, 0, 0);
        }
    };

    // Prologue: A(0)[4], B(0)[2], A(1)[4]; vmcnt(4) -> A(0)+B(0) done, A(1) flying.
    SA(0, 0); SB(0, 0);
    if (NT > 1) SA(1, 1);
    asm volatile("s_waitcnt vmcnt(4)" ::: "memory");
    SCHED_FENCE();
    __builtin_amdgcn_s_barrier();
    SCHED_FENCE();

    int sa = 0;                                           // u % 3
    for (int u = 0; u < NT; ++u) {
        const bf16* Ab = Asl + sa * (256 * 64);
        const bf16* Bb = Bsl + (u & 1) * (128 * 64);

        // ---------- P0 ----------
        bf16x8 bfr[2][2], af[4][2];
        #pragma unroll
        for (int nf = 0; nf < 2; ++nf)
            #pragma unroll
            for (int kh = 0; kh < 2; ++kh) {
                const int r = wn * 32 + nf * 16 + l16;
                const int p = (kh * 4 + quad) ^ (r & 7);
                bfr[nf][kh] = *(const bf16x8*)&Bb[r * 64 + p * 8];
            }
        #pragma unroll
        for (int mf = 0; mf < 4; ++mf)
            #pragma unroll
            for (int kh = 0; kh < 2; ++kh) {
                const int r = wm * 128 + mf * 16 + l16;
                const int p = (kh * 4 + quad) ^ (r & 7);
                af[mf][kh] = *(const bf16x8*)&Ab[r * 64 + p * 8];
            }
        if (u + 1 < NT) SB((u + 1) & 1, u + 1);
        SCHED_FENCE();
        __builtin_amdgcn_s_barrier();
        SCHED_FENCE();
        __builtin_amdgcn_s_setprio(1);
        #pragma unroll
        for (int mf = 0; mf < 4; ++mf)
            #pragma unroll
            for (int nf = 0; nf < 2; ++nf)
                #pragma unroll
                for (int kh = 0; kh < 2; ++kh) {
                    if (vblk) acc[mf][nf] = __builtin_amdgcn_mfma_f32_16x16x32_bf16(af[mf][kh], bfr[nf][kh], acc[mf][nf], 0, 0, 0);
                    else      acc[mf][nf] = __builtin_amdgcn_mfma_f32_16x16x32_bf16(bfr[nf][kh], af[mf][kh], acc[mf][nf], 0, 0, 0);
                }
        __builtin_amdgcn_s_setprio(0);
        SCHED_FENCE();
        __builtin_amdgcn_s_barrier();
        SCHED_FENCE();

        // ---------- P1 ----------
        #pragma unroll
        for (int mf = 0; mf < 4; ++mf)
            #pragma unroll
            for (int kh = 0; kh < 2; ++kh) {
                const int r = wm * 128 + 64 + mf * 16 + l16;
                const int p = (kh * 4 + quad) ^ (r & 7);
                af[mf][kh] = *(const bf16x8*)&Ab[r * 64 + p * 8];
            }
        if (u + 2 < NT) {
            SA(sa == 0 ? 2 : sa - 1, u + 2);              // slot (u+2)%3
            asm volatile("s_waitcnt vmcnt(4)" ::: "memory");
        } else {
            asm volatile("s_waitcnt vmcnt(0)" ::: "memory");
        }
        SCHED_FENCE();
        __builtin_amdgcn_s_barrier();
        SCHED_FENCE();
        __builtin_amdgcn_s_setprio(1);
        #pragma unroll
        for (int mf = 0; mf < 4; ++mf)
            #pragma unroll
            for (int nf = 0; nf < 2; ++nf)
                #pragma unroll
                for (int kh = 0; kh < 2; ++kh) {
                    if (vblk) acc[4 + mf][nf] = __builtin_amdgcn_mfma_f32_16x16x32_bf16(af[mf][kh], bfr[nf][kh], acc[4 + mf][nf], 0, 0, 0);
                    else      acc[4 + mf][nf] = __builtin_amdgcn_mfma_f32_16x16x32_bf16(bfr[nf][kh], af[mf][kh], acc[4 + mf][nf], 0, 0, 0);
                }
        __builtin_amdgcn_s_setprio(0);
        SCHED_FENCE();
        __builtin_amdgcn_s_barrier();
        SCHED_FENCE();

        sa = (sa == 2) ? 0 : sa + 1;
    }

    // ---------------- epilogues ----------------
    if (QKV) {
        bf16* qkv = (bf16*)outp;                 // q base; k at +8M elems, v at +16M
        if (!vblk) {
            const int which = tn >> 9;           // 0=q, 1=k
            bf16* dst = qkv + (size_t)which * (8u << 20);
            #pragma unroll
            for (int mf = 0; mf < 8; ++mf) {
                const int m = tm + wm * 128 + mf * 16 + l16;   // token (C^T: col=m)
                const int bb = m >> 9, t = m & 511;
                #pragma unroll
                for (int nf = 0; nf < 2; ++nf) {
                    const int nb = tn + wn * 32 + nf * 16 + quad * 4;
                    const int hh = (nb >> 6) & 7, dd = nb & 63;
                    short4v pk;
                    #pragma unroll
                    for (int r = 0; r < 4; ++r) pk[r] = f2bf_bits(acc[mf][nf][r]);
                    *(short4v*)&dst[((size_t)(bb * 8 + hh) * 512 + t) * 64 + dd] = pk;
                }
            }
        } else {
            bf16* dst = qkv + (size_t)2 * (8u << 20);
            #pragma unroll
            for (int mf = 0; mf < 8; ++mf) {
                const int mb = tm + wm * 128 + mf * 16 + quad * 4;   // token base
                const int bb = mb >> 9, t = mb & 511;
                #pragma unroll
                for (int nf = 0; nf < 2; ++nf) {
                    const int n = tn + wn * 32 + nf * 16 + l16;
                    const int hh = (n >> 6) & 7, dd = n & 63;
                    short4v pk;
                    #pragma unroll
                    for (int r = 0; r < 4; ++r) pk[r] = f2bf_bits(acc[mf][nf][r]);
                    *(short4v*)&dst[((size_t)(bb * 8 + hh) * 64 + dd) * 512 + t] = pk;
                }
            }
        }
    } else {
        #pragma unroll
        for (int mf = 0; mf < 8; ++mf) {
            const int m = tm + wm * 128 + mf * 16 + l16;             // C^T: col=m
            #pragma unroll
            for (int nf = 0; nf < 2; ++nf) {
                const int nb = tn + wn * 32 + nf * 16 + quad * 4;    // 4 consecutive n
                f32x4 a = acc[mf][nf];
                if (bias) a += *(const f32x4*)&bias[nb];
                if (RELU) {
                    #pragma unroll
                    for (int r = 0; r < 4; ++r) a[r] = fmaxf(a[r], 0.0f);
                }
                if (res)  a += *(const f32x4*)&res[(size_t)m * N + nb];
                if (OUT_BF16) {
                    short4v pk;
                    #pragma unroll
                    for (int r = 0; r < 4; ++r) pk[r] = f2bf_bits(a[r]);
                    *(short4v*)&((bf16*)outp)[(size_t)m * N + nb] = pk;
                } else {
                    *(f32x4*)&((float*)outp)[(size_t)m * N + nb] = a;
                }
            }
        }
    }
}

// ---------------- Flash attention: qt-paired, dbuf global_load_lds -----------
#define ATTN_TILE(qa, m_i, l_i, Of, qw, qtT)                                          \
  do {                                                                                \
    f32x4 Sf[4];                                                                      \
    _Pragma("unroll")                                                                 \
    for (int kf = 0; kf < 4; ++kf) {                                                  \
        const int row = kf * 16 + l16;                                                \
        bf16x8 b0 = *(const bf16x8*)&Ks[cur][row * 64 + ((quad ^ (row & 7)) * 8)];    \
        bf16x8 b1 = *(const bf16x8*)&Ks[cur][row * 64 + (((4 + quad) ^ (row & 7)) * 8)]; \
        f32x4 z = (f32x4){0.f, 0.f, 0.f, 0.f};                                        \
        z = __builtin_amdgcn_mfma_f32_16x16x32_bf16(qa[0], b0, z, 0, 0, 0);           \
        z = __builtin_amdgcn_mfma_f32_16x16x32_bf16(qa[1], b1, z, 0, 0, 0);           \
        Sf[kf] = z;                                                                   \
    }                                                                                 \
    if (kt == qtT) {                                                                  \
        _Pragma("unroll")                                                             \
        for (int kf = 0; kf < 4; ++kf)                                                \
            _Pragma("unroll")                                                         \
            for (int r = 0; r < 4; ++r)                                               \
                if (kt * 64 + kf * 16 + l16 > (qw) + quad * 4 + r) Sf[kf][r] = -1e30f;\
    }                                                                                 \
    float mnew[4], alpha[4];                                                          \
    _Pragma("unroll")                                                                 \
    for (int r = 0; r < 4; ++r) {                                                     \
        float v = fmaxf(fmaxf(Sf[0][r], Sf[1][r]), fmaxf(Sf[2][r], Sf[3][r]));        \
        v = fmaxf(v, __shfl_xor(v, 1, 64));                                           \
        v = fmaxf(v, __shfl_xor(v, 2, 64));                                           \
        v = fmaxf(v, __shfl_xor(v, 4, 64));                                           \
        v = fmaxf(v, __shfl_xor(v, 8, 64));                                           \
        mnew[r]   = fmaxf(m_i[r], v);                                                 \
        alpha[r]  = __expf(m_i[r] - mnew[r]);                                         \
        m_i[r]    = mnew[r];                                                          \
    }                                                                                 \
    float rs[4] = {0.f, 0.f, 0.f, 0.f};                                               \
    _Pragma("unroll")                                                                 \
    for (int kf = 0; kf < 4; ++kf) {                                                  \
        _Pragma("unroll")                                                             \
        for (int r = 0; r < 4; ++r) {                                                 \
            float p = __expf(Sf[kf][r] - mnew[r]);                                    \
            rs[r] += p;                                                               \
            Pw[wave][quad * 4 + r][kf * 16 + l16] = f2bf(p);                          \
        }                                                                             \
    }                                                                                 \
    _Pragma("unroll")                                                                 \
    for (int r = 0; r < 4; ++r) {                                                     \
        rs[r] += __shfl_xor(rs[r], 1, 64);                                            \
        rs[r] += __shfl_xor(rs[r], 2, 64);                                            \
        rs[r] += __shfl_xor(rs[r], 4, 64);                                            \
        rs[r] += __shfl_xor(rs[r], 8, 64);                                            \
        l_i[r] = l_i[r] * alpha[r] + rs[r];                                           \
    }                                                                                 \
    _Pragma("unroll")                                                                 \
    for (int f = 0; f < 4; ++f)                                                       \
        _Pragma("unroll")                                                             \
        for (int r = 0; r < 4; ++r)                                                   \
            Of[f][r] *= alpha[r];                                                     \
    bf16x8 pa0 = *(const bf16x8*)&Pw[wave][l16][quad * 8];                            \
    bf16x8 pa1 = *(const bf16x8*)&Pw[wave][l16][32 + quad * 8];                       \
    _Pragma("unroll")                                                                 \
    for (int f = 0; f < 4; ++f) {                                                     \
        const int vrow = f * 16 + l16;                                                \
        bf16x8 vb0 = *(const bf16x8*)&Vt[cur][vrow * 64 + ((quad ^ (vrow & 7)) * 8)]; \
        bf16x8 vb1 = *(const bf16x8*)&Vt[cur][vrow * 64 + (((4 + quad) ^ (vrow & 7)) * 8)]; \
        Of[f] = __builtin_amdgcn_mfma_f32_16x16x32_bf16(pa0, vb0, Of[f], 0, 0, 0);    \
        Of[f] = __builtin_amdgcn_mfma_f32_16x16x32_bf16(pa1, vb1, Of[f], 0, 0, 0);    \
    }                                                                                 \
  } while (0)

__global__ __launch_bounds__(256, 2) void attn_kernel(const bf16* __restrict__ q,
                                                      const bf16* __restrict__ kM,
                                                      const bf16* __restrict__ vT,
                                                      bf16* __restrict__ o)
{
    __shared__ __align__(16) bf16 Ks[2][64 * 64];
    __shared__ __align__(16) bf16 Vt[2][64 * 64];
    __shared__ __align__(16) bf16 Pw[4][16][72];

    const int tid  = threadIdx.x;
    const int wave = tid >> 6, lane = tid & 63;
    const int l16  = lane & 15, quad = lane >> 4;

    const int nwg = gridDim.x * gridDim.y;
    int bid = blockIdx.y * gridDim.x + blockIdx.x;
    bid = (bid & 7) * (nwg >> 3) + (bid >> 3);
    const int pair = bid & 3;
    const int bh   = bid >> 2;

    const int qt0 = pair, qt1 = 7 - pair;
    const int qw0 = qt0 * 64 + wave * 16;
    const int qw1 = qt1 * 64 + wave * 16;

    const float scale = 0.04419417382415922f;  // C^-0.5 (reference uses n_embd)
    bf16x8 qa0[2], qa1[2];
    #pragma unroll
    for (int c = 0; c < 2; ++c) {
        bf16x8 t0 = *(const bf16x8*)(q + ((size_t)bh * T_ + qw0 + l16) * 64 + c * 32 + quad * 8);
        bf16x8 t1 = *(const bf16x8*)(q + ((size_t)bh * T_ + qw1 + l16) * 64 + c * 32 + quad * 8);
        #pragma unroll
        for (int j = 0; j < 8; ++j) {
            t0[j] = f2bf_bits(bfbits2f(t0[j]) * scale);
            t1[j] = f2bf_bits(bfbits2f(t1[j]) * scale);
        }
        qa0[c] = t0; qa1[c] = t1;
    }

    float m0[4], l0[4], m1[4], l1[4];
    f32x4 O0[4], O1[4];
    #pragma unroll
    for (int r = 0; r < 4; ++r) { m0[r] = -1e30f; l0[r] = 0.f; m1[r] = -1e30f; l1[r] = 0.f; }
    #pragma unroll
    for (int f = 0; f < 4; ++f) { O0[f] = (f32x4){0.f,0.f,0.f,0.f}; O1[f] = (f32x4){0.f,0.f,0.f,0.f}; }

    auto STAGE = [&](int buf, int kt) {
        const int k0 = kt * 64;
        #pragma unroll
        for (int j = 0; j < 2; ++j) {
            const int g = j * 256 + tid;
            const int row = g >> 3, phys = g & 7;
            const int c = phys ^ (row & 7);
            __builtin_amdgcn_global_load_lds((const AS_G void*)(kM + ((size_t)bh * T_ + k0 + row) * 64 + c * 8),
                                             (AS_L void*)&Ks[buf][(size_t)g * 8], 16, 0, 0);
            __builtin_amdgcn_global_load_lds((const AS_G void*)(vT + ((size_t)bh * 64 + row) * T_ + k0 + c * 8),
                                             (AS_L void*)&Vt[buf][(size_t)g * 8], 16, 0, 0);
        }
    };

    STAGE(0, 0);
    __syncthreads();

    int cur = 0;
    for (int kt = 0; kt <= qt1; ++kt) {
        if (kt < qt1) STAGE(cur ^ 1, kt + 1);

        if (kt <= qt0) ATTN_TILE(qa0, m0, l0, O0, qw0, qt0);
        ATTN_TILE(qa1, m1, l1, O1, qw1, qt1);

        __syncthreads();
        cur ^= 1;
    }

    const int b = bh >> 3, hh = bh & 7;
    #pragma unroll
    for (int r = 0; r < 4; ++r) {
        const float inv0 = 1.0f / l0[r];
        const float inv1 = 1.0f / l1[r];
        const int t0 = qw0 + quad * 4 + r;
        const int t1 = qw1 + quad * 4 + r;
        #pragma unroll
        for (int f = 0; f < 4; ++f) {
            o[((size_t)b * T_ + t0) * C_ + hh * 64 + f * 16 + l16] = f2bf(O0[f][r] * inv0);
            o[((size_t)b * T_ + t1) * C_ + hh * 64 + f * 16 + l16] = f2bf(O1[f][r] * inv1);
        }
    }
}

// -----------------------------------------------------------------------------
extern "C" void kernel_launch(void* const* d_in, const int* in_sizes, int n_in,
                              void* d_out, int out_size, void* d_ws, size_t ws_size,
                              hipStream_t stream)
{
    const float* x     = (const float*)d_in[0];
    const float* wq    = (const float*)d_in[1];
    const float* wk    = (const float*)d_in[2];
    const float* wv    = (const float*)d_in[3];
    const float* wproj = (const float*)d_in[4];
    const float* bproj = (const float*)d_in[5];
    const float* w1    = (const float*)d_in[6];
    const float* b1    = (const float*)d_in[7];
    const float* w2    = (const float*)d_in[8];
    const float* b2    = (const float*)d_in[9];
    const float* ln1g  = (const float*)d_in[10];
    const float* ln1b  = (const float*)d_in[11];
    const float* ln2g  = (const float*)d_in[12];
    const float* ln2b  = (const float*)d_in[13];

    char* ws = (char*)d_ws;
    bf16*  h    = (bf16*)(ws + 0);
    bf16*  q    = (bf16*)(ws + ((size_t)16 << 20));
    bf16*  k    = (bf16*)(ws + ((size_t)32 << 20));
    bf16*  v    = (bf16*)(ws + ((size_t)48 << 20));   // (B,H,D,T)
    bf16*  mid  = (bf16*)(ws + 0);
    bf16*  o    = (bf16*)(ws + ((size_t)64 << 20));
    bf16*  h2   = (bf16*)(ws + ((size_t)80 << 20));
    bf16*  wt   = (bf16*)(ws + ((size_t)96 << 20));
    bf16*  projt = wt + (size_t)1536 * 512;
    bf16*  w1t   = wt + (size_t)2048 * 512;
    bf16*  w2t   = wt + (size_t)4096 * 512;
    float* x1    = (float*)d_out;

    // allow 128 KB dynamic LDS on the GEMM instantiations (one-time)
    static bool smem_init = false;
    if (!smem_init) {
        smem_init = true;
        hipFuncSetAttribute(reinterpret_cast<const void*>(&gemm8<true,  false, true >),
                            hipFuncAttributeMaxDynamicSharedMemorySize, 131072);
        hipFuncSetAttribute(reinterpret_cast<const void*>(&gemm8<false, false, false>),
                            hipFuncAttributeMaxDynamicSharedMemorySize, 131072);
        hipFuncSetAttribute(reinterpret_cast<const void*>(&gemm8<false, true,  true >),
                            hipFuncAttributeMaxDynamicSharedMemorySize, 131072);
    }

    // 0. all weight transposes (f32 -> bf16, [N][K])
    transpose_all<<<768, 256, 0, stream>>>(wq, wk, wv, wproj, w1, w2, wt);

    // 1. h = LN1(x)
    ln_kernel<<<BT, 256, 0, stream>>>(x, ln1g, ln1b, h);

    // 2. q|k|v = h @ wqkv  (one N=1536 GEMM; v written (B,H,D,T))
    gemm8<true,  false, true ><<<dim3(12, 64), 512, 131072, stream>>>(h, wt, nullptr, nullptr, q, 1536, 512);

    // 3. o = flash-attn(q,k,v) -> (B,T,C); qt-paired grid
    attn_kernel<<<dim3(4, B_ * H_), 256, 0, stream>>>(q, k, v, o);

    // 4. x1 = x + o @ w_proj + b_proj   (x1 = d_out, f32)
    gemm8<false, false, false><<<dim3(4, 64), 512, 131072, stream>>>(o, projt, bproj, x, x1, 512, 512);

    // 5. h2 = LN2(x1)
    ln_kernel<<<BT, 256, 0, stream>>>(x1, ln2g, ln2b, h2);

    // 6. mid = relu(h2 @ w1 + b1)
    gemm8<false, true,  true ><<<dim3(16, 64), 512, 131072, stream>>>(h2, w1t, b1, nullptr, mid, 2048, 512);

    // 7. out = x1 + mid @ w2 + b2   (in-place on d_out)
    gemm8<false, false, false><<<dim3(4, 64), 512, 131072, stream>>>(mid, w2t, b2, x1, (float*)d_out, 512, 2048);
}

// Round 4
// 349.153 us; speedup vs baseline: 1.0257x; 1.0257x over previous
//
#include <hip/hip_runtime.h>
#include <hip/hip_bf16.h>

// Transformer block: B=32 T=512 C=512 H=8 D=64
// Round 8: QKV + FFN1 -> true 8-phase counted-vmcnt GEMM (m201 template):
//  256x256 tile, BK=64, 512 thr / 8 waves (2Mx4N), per-wave 128x64.
//  8 phases per 2 K-tiles; each phase: {ds_read quadrant | stage 1 half-tile
//  (2x global_load_lds) | barrier | lgkmcnt(0) | setprio1 16xMFMA setprio0 |
//  barrier}. vmcnt(4) ONLY at phases 4 & 8 (completes exactly the 4 halves
//  the next 3 phases read, leaves 4 loads in flight). Ledger-verified
//  free/coverage per half-tile. proj/FFN2 revert to the round-5 2-phase
//  128^2 kernel (coarse 2-phase at 256-wide N beats half-idle GPU).
// Attention/LN/transpose unchanged.

#define B_  32
#define T_  512
#define C_  512
#define H_  8
#define D_  64
#define BT  (B_*T_)      // 16384 rows
#define CF  2048         // 4*C

typedef __hip_bfloat16 bf16;
typedef __attribute__((ext_vector_type(8))) short bf16x8;   // 8 bf16 (4 VGPRs)
typedef __attribute__((ext_vector_type(4))) float f32x4;
typedef __attribute__((ext_vector_type(4))) short short4v;

__device__ __forceinline__ float bf2f(bf16 x) { return __bfloat162float(x); }
__device__ __forceinline__ bf16  f2bf(float x){ return __float2bfloat16(x); }
__device__ __forceinline__ short f2bf_bits(float f){
    bf16 h = __float2bfloat16(f);
    return *reinterpret_cast<short*>(&h);
}
__device__ __forceinline__ float bfbits2f(short s){
    unsigned u = ((unsigned)(unsigned short)s) << 16;
    return __uint_as_float(u);
}

#define AS_G __attribute__((address_space(1)))
#define AS_L __attribute__((address_space(3)))

#define SCHED_FENCE() __builtin_amdgcn_sched_barrier(0)

// ---------------- All weight transposes in one launch ------------------------
__global__ __launch_bounds__(256) void transpose_all(const float* __restrict__ wq,
                                                     const float* __restrict__ wk,
                                                     const float* __restrict__ wv,
                                                     const float* __restrict__ wproj,
                                                     const float* __restrict__ w1,
                                                     const float* __restrict__ w2,
                                                     bf16* __restrict__ wt)
{
    const int t = blockIdx.x;
    const float* src; int K, Nn, k0, n0; size_t dstoff;
    if (t < 192) {
        const int which = t / 64, w = t % 64, hh = w >> 3, kt = w & 7;
        src = (which == 0 ? wq : which == 1 ? wk : wv) + (size_t)hh * 512 * 64;
        K = 512; Nn = 64; k0 = kt * 64; n0 = 0;
        dstoff = (size_t)(which * 512 + hh * 64) * 512;
    } else if (t < 256) {
        const int i = t - 192;
        src = wproj; K = 512; Nn = 512; n0 = (i & 7) * 64; k0 = (i >> 3) * 64;
        dstoff = (size_t)1536 * 512;
    } else if (t < 512) {
        const int i = t - 256;
        src = w1; K = 512; Nn = 2048; n0 = (i & 31) * 64; k0 = (i >> 5) * 64;
        dstoff = (size_t)2048 * 512;
    } else {
        const int i = t - 512;
        src = w2; K = 2048; Nn = 512; n0 = (i & 7) * 64; k0 = (i >> 3) * 64;
        dstoff = (size_t)2048 * 512 + (size_t)2048 * 512;
    }

    __shared__ float tl[64][65];
    const int tid = threadIdx.x;
    #pragma unroll
    for (int j = 0; j < 16; ++j) {
        const int e = j * 256 + tid, r = e >> 6, c = e & 63;
        tl[r][c] = src[(size_t)(k0 + r) * Nn + n0 + c];
    }
    __syncthreads();
    #pragma unroll
    for (int j = 0; j < 16; ++j) {
        const int e = j * 256 + tid, n = e >> 6, kk = e & 63;
        wt[dstoff + (size_t)(n0 + n) * K + k0 + kk] = f2bf(tl[kk][n]);
    }
}

// ---------------- LayerNorm: one block per row (C=512), 256 threads ----------
__global__ __launch_bounds__(256) void ln_kernel(const float* __restrict__ x,
                                                 const float* __restrict__ g,
                                                 const float* __restrict__ b,
                                                 bf16* __restrict__ out)
{
    const int row = blockIdx.x;
    const int tid = threadIdx.x;
    const float* xr = x + (size_t)row * C_;
    float v0 = xr[tid], v1 = xr[tid + 256];

    __shared__ float red[4];

    float s = v0 + v1;
    #pragma unroll
    for (int off = 32; off > 0; off >>= 1) s += __shfl_down(s, off, 64);
    if ((tid & 63) == 0) red[tid >> 6] = s;
    __syncthreads();
    const float mean = (red[0] + red[1] + red[2] + red[3]) * (1.0f / C_);
    __syncthreads();

    float d0 = v0 - mean, d1 = v1 - mean;
    float vs = d0 * d0 + d1 * d1;
    #pragma unroll
    for (int off = 32; off > 0; off >>= 1) vs += __shfl_down(vs, off, 64);
    if ((tid & 63) == 0) red[tid >> 6] = vs;
    __syncthreads();
    const float var  = (red[0] + red[1] + red[2] + red[3]) * (1.0f / C_);
    const float rstd = rsqrtf(var + 1e-5f);

    bf16* orow = out + (size_t)row * C_;
    orow[tid]       = f2bf(d0 * rstd * g[tid]       + b[tid]);
    orow[tid + 256] = f2bf(d1 * rstd * g[tid + 256] + b[tid + 256]);
}

// ---------------- 2-phase 128^2 GEMM (round-5 version; proj + FFN2) ----------
template<bool QKV, bool RELU, bool OUT_BF16>
__global__ __launch_bounds__(256, 2) void mfma_gemm(const bf16* __restrict__ A,
                                                    const bf16* __restrict__ Bt,
                                                    const float* __restrict__ bias,
                                                    const float* __restrict__ res,
                                                    void* __restrict__ outp,
                                                    int N, int K)
{
    __shared__ __align__(16) bf16 As[2][128 * 64];
    __shared__ __align__(16) bf16 Bs[2][128 * 64];

    const int tid  = threadIdx.x;
    const int wave = tid >> 6, lane = tid & 63;
    const int l16  = lane & 15, quad = lane >> 4;
    const int wm   = wave >> 1, wn = wave & 1;

    const int nwg = gridDim.x * gridDim.y;
    int bid = blockIdx.y * gridDim.x + blockIdx.x;
    bid = (bid & 7) * (nwg >> 3) + (bid >> 3);
    const int tn = (bid % gridDim.x) * 128;
    const int tm = (bid / gridDim.x) * 128;
    const bool vblk = QKV && (tn >= 1024);

    f32x4 acc[4][4];
    #pragma unroll
    for (int i = 0; i < 4; ++i)
        #pragma unroll
        for (int j = 0; j < 4; ++j) acc[i][j] = (f32x4){0.f, 0.f, 0.f, 0.f};

    auto STAGE = [&](int buf, int k0) {
        #pragma unroll
        for (int j = 0; j < 4; ++j) {
            const int g = j * 256 + tid;
            const int row = g >> 3, phys = g & 7;
            const int c = phys ^ (row & 7);
            __builtin_amdgcn_global_load_lds((const AS_G void*)(A  + (size_t)(tm + row) * K + k0 + c * 8),
                                             (AS_L void*)&As[buf][(size_t)g * 8], 16, 0, 0);
            __builtin_amdgcn_global_load_lds((const AS_G void*)(Bt + (size_t)(tn + row) * K + k0 + c * 8),
                                             (AS_L void*)&Bs[buf][(size_t)g * 8], 16, 0, 0);
        }
    };

    STAGE(0, 0);
    __syncthreads();

    int cur = 0;
    for (int k0 = 0; k0 < K; k0 += 64) {
        if (k0 + 64 < K) STAGE(cur ^ 1, k0 + 64);

        #pragma unroll
        for (int half = 0; half < 2; ++half) {
            bf16x8 af[4], bfr[4];
            #pragma unroll
            for (int mf = 0; mf < 4; ++mf) {
                const int r = wm * 64 + mf * 16 + l16;
                const int p = (half * 4 + quad) ^ (r & 7);
                af[mf] = *(const bf16x8*)&As[cur][r * 64 + p * 8];
            }
            #pragma unroll
            for (int nf = 0; nf < 4; ++nf) {
                const int r = wn * 64 + nf * 16 + l16;
                const int p = (half * 4 + quad) ^ (r & 7);
                bfr[nf] = *(const bf16x8*)&Bs[cur][r * 64 + p * 8];
            }
            if (vblk) {
                #pragma unroll
                for (int mf = 0; mf < 4; ++mf)
                    #pragma unroll
                    for (int nf = 0; nf < 4; ++nf)
                        acc[mf][nf] = __builtin_amdgcn_mfma_f32_16x16x32_bf16(af[mf], bfr[nf], acc[mf][nf], 0, 0, 0);
            } else {
                #pragma unroll
                for (int mf = 0; mf < 4; ++mf)
                    #pragma unroll
                    for (int nf = 0; nf < 4; ++nf)
                        acc[mf][nf] = __builtin_amdgcn_mfma_f32_16x16x32_bf16(bfr[nf], af[mf], acc[mf][nf], 0, 0, 0);
            }
        }

        __syncthreads();
        cur ^= 1;
    }

    {
        #pragma unroll
        for (int mf = 0; mf < 4; ++mf) {
            const int m = tm + wm * 64 + mf * 16 + l16;
            #pragma unroll
            for (int nf = 0; nf < 4; ++nf) {
                const int nb = tn + wn * 64 + nf * 16 + quad * 4;
                f32x4 a = acc[mf][nf];
                if (bias) a += *(const f32x4*)&bias[nb];
                if (RELU) {
                    #pragma unroll
                    for (int r = 0; r < 4; ++r) a[r] = fmaxf(a[r], 0.0f);
                }
                if (res)  a += *(const f32x4*)&res[(size_t)m * N + nb];
                if (OUT_BF16) {
                    short4v pk;
                    #pragma unroll
                    for (int r = 0; r < 4; ++r) pk[r] = f2bf_bits(a[r]);
                    *(short4v*)&((bf16*)outp)[(size_t)m * N + nb] = pk;
                } else {
                    *(f32x4*)&((float*)outp)[(size_t)m * N + nb] = a;
                }
            }
        }
    }
}

// ---------------- 8-phase counted-vmcnt GEMM (QKV + FFN1) --------------------
// C[M,N] = A[M,K] * Bt[N,K]^T. BM=BN=256, BK=64. 512 thr = 8 waves (2Mx4N),
// per-wave 128x64 out = acc[qm][mf][nf] (qm: 64-row half, mf: 16-row frag,
// nf: 16-col frag). LDS 128 KB dyn: As0|As1|Bs0|Bs1, each [256][64] bf16,
// XOR-8 16B-chunk swizzle, staged as 2 half-tiles (2 global_load_lds each).
// Buffer parity = K-tile parity. Iteration i computes tiles t0=2i (buf0,
// ph1-4) and t1=2i+1 (buf1, ph5-8).
//   ph1: LDA(b0,qm0)+LDB(b0,qn0) | stage A(t1)h0   | MM(0,0)
//   ph2: LDB(b0,qn1)             | stage A(t1)h1   | MM(0,1)
//   ph3: LDA(b0,qm1)             | stage B(t0+2)h0 | MM(1,1)
//   ph4:                         | stage A(t0+2)h0 | vmcnt(4) MM(1,0)
//   ph5: LDA(b1,qm0)+LDB(b1,qn0) | stage A(t0+2)h1 | MM(0,0)
//   ph6: LDB(b1,qn1)             | stage B(t0+2)h1 | MM(0,1)
//   ph7: LDA(b1,qm1)             | stage B(t1+2)h0 | MM(1,1)
//   ph8:                         | stage B(t1+2)h1 | vmcnt(4) MM(1,0)
// Ledger: every region is restaged >=1 barrier after its last read
// (B free after its qn1 read, A after qm1); vmcnt(4) at ph4/ph8 completes
// exactly the 4 halves the following 3 phases read, leaving 4 loads in
// flight. Last iteration: ph4 -> vmcnt(0) (prefetches absent).
template<bool QKV, bool RELU, bool OUT_BF16>
__global__ __launch_bounds__(512, 2) void gemm8ph(const bf16* __restrict__ A,
                                                  const bf16* __restrict__ Bt,
                                                  const float* __restrict__ bias,
                                                  const float* __restrict__ res,
                                                  void* __restrict__ outp,
                                                  int N, int K)
{
    extern __shared__ __align__(16) char smem[];
    bf16* const As0 = (bf16*)smem;
    bf16* const As1 = As0 + 256 * 64;
    bf16* const Bs0 = As1 + 256 * 64;
    bf16* const Bs1 = Bs0 + 256 * 64;

    const int tid  = threadIdx.x;
    const int lane = tid & 63, wid = tid >> 6;
    const int l16  = lane & 15, quad = lane >> 4;
    const int wm   = wid >> 2, wn = wid & 3;

    const int gridx = gridDim.x;
    const int nwg   = gridx * gridDim.y;
    int bid = blockIdx.y * gridx + blockIdx.x;
    bid = (bid & 7) * (nwg >> 3) + (bid >> 3);            // bijective XCD swizzle
    const int tn = (bid % gridx) * 256;
    const int tm = (bid / gridx) * 256;
    const bool vblk = QKV && (tn >= 1024);
    const int NT = K >> 6, NI = NT >> 1;                  // NT even for all our K

    f32x4 acc[2][4][4];
    #pragma unroll
    for (int q = 0; q < 2; ++q)
        #pragma unroll
        for (int i = 0; i < 4; ++i)
            #pragma unroll
            for (int j = 0; j < 4; ++j) acc[q][i][j] = (f32x4){0.f, 0.f, 0.f, 0.f};

    bf16x8 af[4][2], bfr[4][2];

#define SA8(dst, u, h) do {                                                          \
    const int _k0 = (u) << 6;                                                        \
    _Pragma("unroll")                                                                \
    for (int _j = 0; _j < 2; ++_j) {                                                 \
        const int _g = (h) * 1024 + _j * 512 + tid;                                  \
        const int _r = _g >> 3, _p = _g & 7;                                         \
        const int _c = _p ^ (_r & 7);                                                \
        __builtin_amdgcn_global_load_lds((const AS_G void*)(A + (size_t)(tm + _r) * K + _k0 + _c * 8), \
                                         (AS_L void*)((dst) + _g * 8), 16, 0, 0);    \
    } } while (0)

#define SB8(dst, u, h) do {                                                          \
    const int _k0 = (u) << 6;                                                        \
    _Pragma("unroll")                                                                \
    for (int _j = 0; _j < 2; ++_j) {                                                 \
        const int _g = (h) * 1024 + _j * 512 + tid;                                  \
        const int _r = _g >> 3, _p = _g & 7;                                         \
        const int _c = _p ^ (_r & 7);                                                \
        __builtin_amdgcn_global_load_lds((const AS_G void*)(Bt + (size_t)(tn + _r) * K + _k0 + _c * 8), \
                                         (AS_L void*)((dst) + _g * 8), 16, 0, 0);    \
    } } while (0)

#define LDA8(Ab, qm) do {                                                            \
    _Pragma("unroll")                                                                \
    for (int _mf = 0; _mf < 4; ++_mf)                                                \
        _Pragma("unroll")                                                            \
        for (int _kh = 0; _kh < 2; ++_kh) {                                          \
            const int _r = wm * 128 + (qm) * 64 + _mf * 16 + l16;                    \
            const int _p = (_kh * 4 + quad) ^ (_r & 7);                              \
            af[_mf][_kh] = *(const bf16x8*)&(Ab)[_r * 64 + _p * 8];                  \
        } } while (0)

#define LDB8(Bb, qn) do {                                                            \
    _Pragma("unroll")                                                                \
    for (int _c2 = 0; _c2 < 2; ++_c2)                                                \
        _Pragma("unroll")                                                            \
        for (int _kh = 0; _kh < 2; ++_kh) {                                          \
            const int _nf = (qn) * 2 + _c2;                                          \
            const int _r = wn * 64 + _nf * 16 + l16;                                 \
            const int _p = (_kh * 4 + quad) ^ (_r & 7);                              \
            bfr[_nf][_kh] = *(const bf16x8*)&(Bb)[_r * 64 + _p * 8];                 \
        } } while (0)

#define MM8(qm, qn) do {                                                             \
    __builtin_amdgcn_s_setprio(1);                                                   \
    _Pragma("unroll")                                                                \
    for (int _mf = 0; _mf < 4; ++_mf)                                                \
        _Pragma("unroll")                                                            \
        for (int _c2 = 0; _c2 < 2; ++_c2) {                                          \
            const int _nf = (qn) * 2 + _c2;                                          \
            _Pragma("unroll")                                                        \
            for (int _kh = 0; _kh < 2; ++_kh) {                                      \
                if (vblk) acc[qm][_mf][_nf] = __builtin_amdgcn_mfma_f32_16x16x32_bf16(af[_mf][_kh], bfr[_nf][_kh], acc[qm][_mf][_nf], 0, 0, 0); \
                else      acc[qm][_mf][_nf] = __builtin_amdgcn_mfma_f32_16x16x32_bf16(bfr[_nf][_kh], af[_mf][_kh], acc[qm][_mf][_nf], 0, 0, 0); \
            }                                                                        \
        }                                                                            \
    __builtin_amdgcn_s_setprio(0);                                                   \
    } while (0)

#define GATE8() do { SCHED_FENCE(); __builtin_amdgcn_s_barrier();                    \
    asm volatile("s_waitcnt lgkmcnt(0)" ::: "memory"); SCHED_FENCE(); } while (0)
#define ENDP8() do { SCHED_FENCE(); __builtin_amdgcn_s_barrier(); SCHED_FENCE(); } while (0)

    // Prologue: A(0) both halves, B(0) both halves, B(1) both halves.
    // vmcnt(4): A(0)+B(0) complete, B(1)'s 4 loads in flight.
    SA8(As0, 0, 0); SA8(As0, 0, 1);
    SB8(Bs0, 0, 0); SB8(Bs0, 0, 1);
    SB8(Bs1, 1, 0); SB8(Bs1, 1, 1);
    asm volatile("s_waitcnt vmcnt(4)" ::: "memory");
    SCHED_FENCE();
    __builtin_amdgcn_s_barrier();
    SCHED_FENCE();

    for (int i = 0; i < NI; ++i) {
        const int t1 = 2 * i + 1, t2 = 2 * i + 2, t3 = 2 * i + 3;
        const bool p2 = t2 < NT, p3 = t3 < NT, lastI = (i == NI - 1);

        // ---- ph1 ----
        LDA8(As0, 0); LDB8(Bs0, 0);
        SA8(As1, t1, 0);
        GATE8(); MM8(0, 0); ENDP8();
        // ---- ph2 ----
        LDB8(Bs0, 1);
        SA8(As1, t1, 1);
        GATE8(); MM8(0, 1); ENDP8();
        // ---- ph3 ----
        LDA8(As0, 1);
        if (p2) SB8(Bs0, t2, 0);
        GATE8(); MM8(1, 1); ENDP8();
        // ---- ph4 ----
        if (p2) SA8(As0, t2, 0);
        if (lastI) asm volatile("s_waitcnt vmcnt(0)" ::: "memory");
        else       asm volatile("s_waitcnt vmcnt(4)" ::: "memory");
        GATE8(); MM8(1, 0); ENDP8();
        // ---- ph5 ----
        LDA8(As1, 0); LDB8(Bs1, 0);
        if (p2) SA8(As0, t2, 1);
        GATE8(); MM8(0, 0); ENDP8();
        // ---- ph6 ----
        LDB8(Bs1, 1);
        if (p2) SB8(Bs0, t2, 1);
        GATE8(); MM8(0, 1); ENDP8();
        // ---- ph7 ----
        LDA8(As1, 1);
        if (p3) SB8(Bs1, t3, 0);
        GATE8(); MM8(1, 1); ENDP8();
        // ---- ph8 ----
        if (p3) SB8(Bs1, t3, 1);
        if (lastI) asm volatile("s_waitcnt vmcnt(0)" ::: "memory");
        else       asm volatile("s_waitcnt vmcnt(4)" ::: "memory");
        GATE8(); MM8(1, 0); ENDP8();
    }

#undef SA8
#undef SB8
#undef LDA8
#undef LDB8
#undef MM8
#undef GATE8
#undef ENDP8

    // ---------------- epilogues ----------------
    if (QKV) {
        bf16* qkv = (bf16*)outp;                 // q base; k at +8M elems, v at +16M
        if (!vblk) {
            const int which = tn >> 9;           // 0=q, 1=k
            bf16* dst = qkv + (size_t)which * (8u << 20);
            #pragma unroll
            for (int qm = 0; qm < 2; ++qm)
                #pragma unroll
                for (int mf = 0; mf < 4; ++mf) {
                    const int m = tm + wm * 128 + qm * 64 + mf * 16 + l16;   // token
                    const int bb = m >> 9, t = m & 511;
                    #pragma unroll
                    for (int nf = 0; nf < 4; ++nf) {
                        const int nb = tn + wn * 64 + nf * 16 + quad * 4;
                        const int hh = (nb >> 6) & 7, dd = nb & 63;
                        short4v pk;
                        #pragma unroll
                        for (int r = 0; r < 4; ++r) pk[r] = f2bf_bits(acc[qm][mf][nf][r]);
                        *(short4v*)&dst[((size_t)(bb * 8 + hh) * 512 + t) * 64 + dd] = pk;
                    }
                }
        } else {
            bf16* dst = qkv + (size_t)2 * (8u << 20);
            #pragma unroll
            for (int qm = 0; qm < 2; ++qm)
                #pragma unroll
                for (int mf = 0; mf < 4; ++mf) {
                    const int mb = tm + wm * 128 + qm * 64 + mf * 16 + quad * 4;  // token base
                    const int bb = mb >> 9, t = mb & 511;
                    #pragma unroll
                    for (int nf = 0; nf < 4; ++nf) {
                        const int n = tn + wn * 64 + nf * 16 + l16;
                        const int hh = (n >> 6) & 7, dd = n & 63;
                        short4v pk;
                        #pragma unroll
                        for (int r = 0; r < 4; ++r) pk[r] = f2bf_bits(acc[qm][mf][nf][r]);
                        *(short4v*)&dst[((size_t)(bb * 8 + hh) * 64 + dd) * 512 + t] = pk;
                    }
                }
        }
    } else {
        #pragma unroll
        for (int qm = 0; qm < 2; ++qm)
            #pragma unroll
            for (int mf = 0; mf < 4; ++mf) {
                const int m = tm + wm * 128 + qm * 64 + mf * 16 + l16;
                #pragma unroll
                for (int nf = 0; nf < 4; ++nf) {
                    const int nb = tn + wn * 64 + nf * 16 + quad * 4;
                    f32x4 a = acc[qm][mf][nf];
                    if (bias) a += *(const f32x4*)&bias[nb];
                    if (RELU) {
                        #pragma unroll
                        for (int r = 0; r < 4; ++r) a[r] = fmaxf(a[r], 0.0f);
                    }
                    if (res)  a += *(const f32x4*)&res[(size_t)m * N + nb];
                    if (OUT_BF16) {
                        short4v pk;
                        #pragma unroll
                        for (int r = 0; r < 4; ++r) pk[r] = f2bf_bits(a[r]);
                        *(short4v*)&((bf16*)outp)[(size_t)m * N + nb] = pk;
                    } else {
                        *(f32x4*)&((float*)outp)[(size_t)m * N + nb] = a;
                    }
                }
            }
    }
}

// ---------------- Flash attention: qt-paired, dbuf global_load_lds -----------
#define ATTN_TILE(qa, m_i, l_i, Of, qw, qtT)                                          \
  do {                                                                                \
    f32x4 Sf[4];                                                                      \
    _Pragma("unroll")                                                                 \
    for (int kf = 0; kf < 4; ++kf) {                                                  \
        const int row = kf * 16 + l16;                                                \
        bf16x8 b0 = *(const bf16x8*)&Ks[cur][row * 64 + ((quad ^ (row & 7)) * 8)];    \
        bf16x8 b1 = *(const bf16x8*)&Ks[cur][row * 64 + (((4 + quad) ^ (row & 7)) * 8)]; \
        f32x4 z = (f32x4){0.f, 0.f, 0.f, 0.f};                                        \
        z = __builtin_amdgcn_mfma_f32_16x16x32_bf16(qa[0], b0, z, 0, 0, 0);           \
        z = __builtin_amdgcn_mfma_f32_16x16x32_bf16(qa[1], b1, z, 0, 0, 0);           \
        Sf[kf] = z;                                                                   \
    }                                                                                 \
    if (kt == qtT) {                                                                  \
        _Pragma("unroll")                                                             \
        for (int kf = 0; kf < 4; ++kf)                                                \
            _Pragma("unroll")                                                         \
            for (int r = 0; r < 4; ++r)                                               \
                if (kt * 64 + kf * 16 + l16 > (qw) + quad * 4 + r) Sf[kf][r] = -1e30f;\
    }                                                                                 \
    float mnew[4], alpha[4];                                                          \
    _Pragma("unroll")                                                                 \
    for (int r = 0; r < 4; ++r) {                                                     \
        float v = fmaxf(fmaxf(Sf[0][r], Sf[1][r]), fmaxf(Sf[2][r], Sf[3][r]));        \
        v = fmaxf(v, __shfl_xor(v, 1, 64));                                           \
        v = fmaxf(v, __shfl_xor(v, 2, 64));                                           \
        v = fmaxf(v, __shfl_xor(v, 4, 64));                                           \
        v = fmaxf(v, __shfl_xor(v, 8, 64));                                           \
        mnew[r]   = fmaxf(m_i[r], v);                                                 \
        alpha[r]  = __expf(m_i[r] - mnew[r]);                                         \
        m_i[r]    = mnew[r];                                                          \
    }                                                                                 \
    float rs[4] = {0.f, 0.f, 0.f, 0.f};                                               \
    _Pragma("unroll")                                                                 \
    for (int kf = 0; kf < 4; ++kf) {                                                  \
        _Pragma("unroll")                                                             \
        for (int r = 0; r < 4; ++r) {                                                 \
            float p = __expf(Sf[kf][r] - mnew[r]);                                    \
            rs[r] += p;                                                               \
            Pw[wave][quad * 4 + r][kf * 16 + l16] = f2bf(p);                          \
        }                                                                             \
    }                                                                                 \
    _Pragma("unroll")                                                                 \
    for (int r = 0; r < 4; ++r) {                                                     \
        rs[r] += __shfl_xor(rs[r], 1, 64);                                            \
        rs[r] += __shfl_xor(rs[r], 2, 64);                                            \
        rs[r] += __shfl_xor(rs[r], 4, 64);                                            \
        rs[r] += __shfl_xor(rs[r], 8, 64);                                            \
        l_i[r] = l_i[r] * alpha[r] + rs[r];                                           \
    }                                                                                 \
    _Pragma("unroll")                                                                 \
    for (int f = 0; f < 4; ++f)                                                       \
        _Pragma("unroll")                                                             \
        for (int r = 0; r < 4; ++r)                                                   \
            Of[f][r] *= alpha[r];                                                     \
    bf16x8 pa0 = *(const bf16x8*)&Pw[wave][l16][quad * 8];                            \
    bf16x8 pa1 = *(const bf16x8*)&Pw[wave][l16][32 + quad * 8];                       \
    _Pragma("unroll")                                                                 \
    for (int f = 0; f < 4; ++f) {                                                     \
        const int vrow = f * 16 + l16;                                                \
        bf16x8 vb0 = *(const bf16x8*)&Vt[cur][vrow * 64 + ((quad ^ (vrow & 7)) * 8)]; \
        bf16x8 vb1 = *(const bf16x8*)&Vt[cur][vrow * 64 + (((4 + quad) ^ (vrow & 7)) * 8)]; \
        Of[f] = __builtin_amdgcn_mfma_f32_16x16x32_bf16(pa0, vb0, Of[f], 0, 0, 0);    \
        Of[f] = __builtin_amdgcn_mfma_f32_16x16x32_bf16(pa1, vb1, Of[f], 0, 0, 0);    \
    }                                                                                 \
  } while (0)

__global__ __launch_bounds__(256, 2) void attn_kernel(const bf16* __restrict__ q,
                                                      const bf16* __restrict__ kM,
                                                      const bf16* __restrict__ vT,
                                                      bf16* __restrict__ o)
{
    __shared__ __align__(16) bf16 Ks[2][64 * 64];
    __shared__ __align__(16) bf16 Vt[2][64 * 64];
    __shared__ __align__(16) bf16 Pw[4][16][72];

    const int tid  = threadIdx.x;
    const int wave = tid >> 6, lane = tid & 63;
    const int l16  = lane & 15, quad = lane >> 4;

    const int nwg = gridDim.x * gridDim.y;
    int bid = blockIdx.y * gridDim.x + blockIdx.x;
    bid = (bid & 7) * (nwg >> 3) + (bid >> 3);
    const int pair = bid & 3;
    const int bh   = bid >> 2;

    const int qt0 = pair, qt1 = 7 - pair;
    const int qw0 = qt0 * 64 + wave * 16;
    const int qw1 = qt1 * 64 + wave * 16;

    const float scale = 0.04419417382415922f;  // C^-0.5 (reference uses n_embd)
    bf16x8 qa0[2], qa1[2];
    #pragma unroll
    for (int c = 0; c < 2; ++c) {
        bf16x8 t0 = *(const bf16x8*)(q + ((size_t)bh * T_ + qw0 + l16) * 64 + c * 32 + quad * 8);
        bf16x8 t1 = *(const bf16x8*)(q + ((size_t)bh * T_ + qw1 + l16) * 64 + c * 32 + quad * 8);
        #pragma unroll
        for (int j = 0; j < 8; ++j) {
            t0[j] = f2bf_bits(bfbits2f(t0[j]) * scale);
            t1[j] = f2bf_bits(bfbits2f(t1[j]) * scale);
        }
        qa0[c] = t0; qa1[c] = t1;
    }

    float m0[4], l0[4], m1[4], l1[4];
    f32x4 O0[4], O1[4];
    #pragma unroll
    for (int r = 0; r < 4; ++r) { m0[r] = -1e30f; l0[r] = 0.f; m1[r] = -1e30f; l1[r] = 0.f; }
    #pragma unroll
    for (int f = 0; f < 4; ++f) { O0[f] = (f32x4){0.f,0.f,0.f,0.f}; O1[f] = (f32x4){0.f,0.f,0.f,0.f}; }

    auto STAGE = [&](int buf, int kt) {
        const int k0 = kt * 64;
        #pragma unroll
        for (int j = 0; j < 2; ++j) {
            const int g = j * 256 + tid;
            const int row = g >> 3, phys = g & 7;
            const int c = phys ^ (row & 7);
            __builtin_amdgcn_global_load_lds((const AS_G void*)(kM + ((size_t)bh * T_ + k0 + row) * 64 + c * 8),
                                             (AS_L void*)&Ks[buf][(size_t)g * 8], 16, 0, 0);
            __builtin_amdgcn_global_load_lds((const AS_G void*)(vT + ((size_t)bh * 64 + row) * T_ + k0 + c * 8),
                                             (AS_L void*)&Vt[buf][(size_t)g * 8], 16, 0, 0);
        }
    };

    STAGE(0, 0);
    __syncthreads();

    int cur = 0;
    for (int kt = 0; kt <= qt1; ++kt) {
        if (kt < qt1) STAGE(cur ^ 1, kt + 1);

        if (kt <= qt0) ATTN_TILE(qa0, m0, l0, O0, qw0, qt0);
        ATTN_TILE(qa1, m1, l1, O1, qw1, qt1);

        __syncthreads();
        cur ^= 1;
    }

    const int b = bh >> 3, hh = bh & 7;
    #pragma unroll
    for (int r = 0; r < 4; ++r) {
        const float inv0 = 1.0f / l0[r];
        const float inv1 = 1.0f / l1[r];
        const int t0 = qw0 + quad * 4 + r;
        const int t1 = qw1 + quad * 4 + r;
        #pragma unroll
        for (int f = 0; f < 4; ++f) {
            o[((size_t)b * T_ + t0) * C_ + hh * 64 + f * 16 + l16] = f2bf(O0[f][r] * inv0);
            o[((size_t)b * T_ + t1) * C_ + hh * 64 + f * 16 + l16] = f2bf(O1[f][r] * inv1);
        }
    }
}

// -----------------------------------------------------------------------------
extern "C" void kernel_launch(void* const* d_in, const int* in_sizes, int n_in,
                              void* d_out, int out_size, void* d_ws, size_t ws_size,
                              hipStream_t stream)
{
    const float* x     = (const float*)d_in[0];
    const float* wq    = (const float*)d_in[1];
    const float* wk    = (const float*)d_in[2];
    const float* wv    = (const float*)d_in[3];
    const float* wproj = (const float*)d_in[4];
    const float* bproj = (const float*)d_in[5];
    const float* w1    = (const float*)d_in[6];
    const float* b1    = (const float*)d_in[7];
    const float* w2    = (const float*)d_in[8];
    const float* b2    = (const float*)d_in[9];
    const float* ln1g  = (const float*)d_in[10];
    const float* ln1b  = (const float*)d_in[11];
    const float* ln2g  = (const float*)d_in[12];
    const float* ln2b  = (const float*)d_in[13];

    char* ws = (char*)d_ws;
    bf16*  h    = (bf16*)(ws + 0);
    bf16*  q    = (bf16*)(ws + ((size_t)16 << 20));
    bf16*  k    = (bf16*)(ws + ((size_t)32 << 20));
    bf16*  v    = (bf16*)(ws + ((size_t)48 << 20));   // (B,H,D,T)
    bf16*  mid  = (bf16*)(ws + 0);
    bf16*  o    = (bf16*)(ws + ((size_t)64 << 20));
    bf16*  h2   = (bf16*)(ws + ((size_t)80 << 20));
    bf16*  wt   = (bf16*)(ws + ((size_t)96 << 20));
    bf16*  projt = wt + (size_t)1536 * 512;
    bf16*  w1t   = wt + (size_t)2048 * 512;
    bf16*  w2t   = wt + (size_t)4096 * 512;
    float* x1    = (float*)d_out;

    // allow 128 KB dynamic LDS on the 8-phase GEMM instantiations (one-time)
    static bool smem_init = false;
    if (!smem_init) {
        smem_init = true;
        hipFuncSetAttribute(reinterpret_cast<const void*>(&gemm8ph<true,  false, true>),
                            hipFuncAttributeMaxDynamicSharedMemorySize, 131072);
        hipFuncSetAttribute(reinterpret_cast<const void*>(&gemm8ph<false, true,  true>),
                            hipFuncAttributeMaxDynamicSharedMemorySize, 131072);
    }

    // 0. all weight transposes (f32 -> bf16, [N][K])
    transpose_all<<<768, 256, 0, stream>>>(wq, wk, wv, wproj, w1, w2, wt);

    // 1. h = LN1(x)
    ln_kernel<<<BT, 256, 0, stream>>>(x, ln1g, ln1b, h);

    // 2. q|k|v = h @ wqkv  (one N=1536 GEMM; v written (B,H,D,T)); 8-phase
    gemm8ph<true,  false, true><<<dim3(6, 64), 512, 131072, stream>>>(h, wt, nullptr, nullptr, q, 1536, 512);

    // 3. o = flash-attn(q,k,v) -> (B,T,C); qt-paired grid
    attn_kernel<<<dim3(4, B_ * H_), 256, 0, stream>>>(q, k, v, o);

    // 4. x1 = x + o @ w_proj + b_proj   (x1 = d_out, f32); 2-phase 128^2
    mfma_gemm<false, false, false><<<dim3(4, 128), 256, 0, stream>>>(o, projt, bproj, x, x1, 512, 512);

    // 5. h2 = LN2(x1)
    ln_kernel<<<BT, 256, 0, stream>>>(x1, ln2g, ln2b, h2);

    // 6. mid = relu(h2 @ w1 + b1); 8-phase
    gemm8ph<false, true,  true><<<dim3(8, 64), 512, 131072, stream>>>(h2, w1t, b1, nullptr, mid, 2048, 512);

    // 7. out = x1 + mid @ w2 + b2   (in-place on d_out); 2-phase 128^2
    mfma_gemm<false, false, false><<<dim3(4, 128), 256, 0, stream>>>(mid, w2t, b2, x1, (float*)d_out, 512, 2048);
}

// Round 6
// 343.942 us; speedup vs baseline: 1.0413x; 1.0152x over previous
//
#include <hip/hip_runtime.h>
#include <hip/hip_bf16.h>

// Transformer block: B=32 T=512 C=512 H=8 D=64
// Round 10 = Round 9 with the compile fix: no LDS pointer arrays (they forced
// an unsupported addrspacecast static initializer); buffers selected by offset
// arithmetic off one base pointer instead.
//  - gemm4ph: BM=256 BN=128 BK=64, 512 thr / 8 waves, 2 phases/K-tile,
//    counted vmcnt(4), distance-2 prefetch, 96 KB LDS. QKV (grid 768 = 3
//    exact CU-waves) and FFN2 (grid 256 = 1 exact wave, NT=32).
//  - FFN1 keeps 256^2 8-phase (512 blocks = 2 exact waves).
//  - proj keeps 2-phase 128^2.
// Attention/LN/transpose unchanged.

#define B_  32
#define T_  512
#define C_  512
#define H_  8
#define D_  64
#define BT  (B_*T_)      // 16384 rows
#define CF  2048         // 4*C

typedef __hip_bfloat16 bf16;
typedef __attribute__((ext_vector_type(8))) short bf16x8;   // 8 bf16 (4 VGPRs)
typedef __attribute__((ext_vector_type(4))) float f32x4;
typedef __attribute__((ext_vector_type(4))) short short4v;

__device__ __forceinline__ float bf2f(bf16 x) { return __bfloat162float(x); }
__device__ __forceinline__ bf16  f2bf(float x){ return __float2bfloat16(x); }
__device__ __forceinline__ short f2bf_bits(float f){
    bf16 h = __float2bfloat16(f);
    return *reinterpret_cast<short*>(&h);
}
__device__ __forceinline__ float bfbits2f(short s){
    unsigned u = ((unsigned)(unsigned short)s) << 16;
    return __uint_as_float(u);
}

#define AS_G __attribute__((address_space(1)))
#define AS_L __attribute__((address_space(3)))

#define SCHED_FENCE() __builtin_amdgcn_sched_barrier(0)

// ---------------- All weight transposes in one launch ------------------------
__global__ __launch_bounds__(256) void transpose_all(const float* __restrict__ wq,
                                                     const float* __restrict__ wk,
                                                     const float* __restrict__ wv,
                                                     const float* __restrict__ wproj,
                                                     const float* __restrict__ w1,
                                                     const float* __restrict__ w2,
                                                     bf16* __restrict__ wt)
{
    const int t = blockIdx.x;
    const float* src; int K, Nn, k0, n0; size_t dstoff;
    if (t < 192) {
        const int which = t / 64, w = t % 64, hh = w >> 3, kt = w & 7;
        src = (which == 0 ? wq : which == 1 ? wk : wv) + (size_t)hh * 512 * 64;
        K = 512; Nn = 64; k0 = kt * 64; n0 = 0;
        dstoff = (size_t)(which * 512 + hh * 64) * 512;
    } else if (t < 256) {
        const int i = t - 192;
        src = wproj; K = 512; Nn = 512; n0 = (i & 7) * 64; k0 = (i >> 3) * 64;
        dstoff = (size_t)1536 * 512;
    } else if (t < 512) {
        const int i = t - 256;
        src = w1; K = 512; Nn = 2048; n0 = (i & 31) * 64; k0 = (i >> 5) * 64;
        dstoff = (size_t)2048 * 512;
    } else {
        const int i = t - 512;
        src = w2; K = 2048; Nn = 512; n0 = (i & 7) * 64; k0 = (i >> 3) * 64;
        dstoff = (size_t)2048 * 512 + (size_t)2048 * 512;
    }

    __shared__ float tl[64][65];
    const int tid = threadIdx.x;
    #pragma unroll
    for (int j = 0; j < 16; ++j) {
        const int e = j * 256 + tid, r = e >> 6, c = e & 63;
        tl[r][c] = src[(size_t)(k0 + r) * Nn + n0 + c];
    }
    __syncthreads();
    #pragma unroll
    for (int j = 0; j < 16; ++j) {
        const int e = j * 256 + tid, n = e >> 6, kk = e & 63;
        wt[dstoff + (size_t)(n0 + n) * K + k0 + kk] = f2bf(tl[kk][n]);
    }
}

// ---------------- LayerNorm: one block per row (C=512), 256 threads ----------
__global__ __launch_bounds__(256) void ln_kernel(const float* __restrict__ x,
                                                 const float* __restrict__ g,
                                                 const float* __restrict__ b,
                                                 bf16* __restrict__ out)
{
    const int row = blockIdx.x;
    const int tid = threadIdx.x;
    const float* xr = x + (size_t)row * C_;
    float v0 = xr[tid], v1 = xr[tid + 256];

    __shared__ float red[4];

    float s = v0 + v1;
    #pragma unroll
    for (int off = 32; off > 0; off >>= 1) s += __shfl_down(s, off, 64);
    if ((tid & 63) == 0) red[tid >> 6] = s;
    __syncthreads();
    const float mean = (red[0] + red[1] + red[2] + red[3]) * (1.0f / C_);
    __syncthreads();

    float d0 = v0 - mean, d1 = v1 - mean;
    float vs = d0 * d0 + d1 * d1;
    #pragma unroll
    for (int off = 32; off > 0; off >>= 1) vs += __shfl_down(vs, off, 64);
    if ((tid & 63) == 0) red[tid >> 6] = vs;
    __syncthreads();
    const float var  = (red[0] + red[1] + red[2] + red[3]) * (1.0f / C_);
    const float rstd = rsqrtf(var + 1e-5f);

    bf16* orow = out + (size_t)row * C_;
    orow[tid]       = f2bf(d0 * rstd * g[tid]       + b[tid]);
    orow[tid + 256] = f2bf(d1 * rstd * g[tid + 256] + b[tid + 256]);
}

// ---------------- 2-phase 128^2 GEMM (proj) ----------------------------------
template<bool QKV, bool RELU, bool OUT_BF16>
__global__ __launch_bounds__(256, 2) void mfma_gemm(const bf16* __restrict__ A,
                                                    const bf16* __restrict__ Bt,
                                                    const float* __restrict__ bias,
                                                    const float* __restrict__ res,
                                                    void* __restrict__ outp,
                                                    int N, int K)
{
    __shared__ __align__(16) bf16 As[2][128 * 64];
    __shared__ __align__(16) bf16 Bs[2][128 * 64];

    const int tid  = threadIdx.x;
    const int wave = tid >> 6, lane = tid & 63;
    const int l16  = lane & 15, quad = lane >> 4;
    const int wm   = wave >> 1, wn = wave & 1;

    const int nwg = gridDim.x * gridDim.y;
    int bid = blockIdx.y * gridDim.x + blockIdx.x;
    bid = (bid & 7) * (nwg >> 3) + (bid >> 3);
    const int tn = (bid % gridDim.x) * 128;
    const int tm = (bid / gridDim.x) * 128;

    f32x4 acc[4][4];
    #pragma unroll
    for (int i = 0; i < 4; ++i)
        #pragma unroll
        for (int j = 0; j < 4; ++j) acc[i][j] = (f32x4){0.f, 0.f, 0.f, 0.f};

    auto STAGE = [&](int buf, int k0) {
        #pragma unroll
        for (int j = 0; j < 4; ++j) {
            const int g = j * 256 + tid;
            const int row = g >> 3, phys = g & 7;
            const int c = phys ^ (row & 7);
            __builtin_amdgcn_global_load_lds((const AS_G void*)(A  + (size_t)(tm + row) * K + k0 + c * 8),
                                             (AS_L void*)&As[buf][(size_t)g * 8], 16, 0, 0);
            __builtin_amdgcn_global_load_lds((const AS_G void*)(Bt + (size_t)(tn + row) * K + k0 + c * 8),
                                             (AS_L void*)&Bs[buf][(size_t)g * 8], 16, 0, 0);
        }
    };

    STAGE(0, 0);
    __syncthreads();

    int cur = 0;
    for (int k0 = 0; k0 < K; k0 += 64) {
        if (k0 + 64 < K) STAGE(cur ^ 1, k0 + 64);

        #pragma unroll
        for (int half = 0; half < 2; ++half) {
            bf16x8 af[4], bfr[4];
            #pragma unroll
            for (int mf = 0; mf < 4; ++mf) {
                const int r = wm * 64 + mf * 16 + l16;
                const int p = (half * 4 + quad) ^ (r & 7);
                af[mf] = *(const bf16x8*)&As[cur][r * 64 + p * 8];
            }
            #pragma unroll
            for (int nf = 0; nf < 4; ++nf) {
                const int r = wn * 64 + nf * 16 + l16;
                const int p = (half * 4 + quad) ^ (r & 7);
                bfr[nf] = *(const bf16x8*)&Bs[cur][r * 64 + p * 8];
            }
            #pragma unroll
            for (int mf = 0; mf < 4; ++mf)
                #pragma unroll
                for (int nf = 0; nf < 4; ++nf)
                    acc[mf][nf] = __builtin_amdgcn_mfma_f32_16x16x32_bf16(bfr[nf], af[mf], acc[mf][nf], 0, 0, 0);
        }

        __syncthreads();
        cur ^= 1;
    }

    {
        #pragma unroll
        for (int mf = 0; mf < 4; ++mf) {
            const int m = tm + wm * 64 + mf * 16 + l16;
            #pragma unroll
            for (int nf = 0; nf < 4; ++nf) {
                const int nb = tn + wn * 64 + nf * 16 + quad * 4;
                f32x4 a = acc[mf][nf];
                if (bias) a += *(const f32x4*)&bias[nb];
                if (RELU) {
                    #pragma unroll
                    for (int r = 0; r < 4; ++r) a[r] = fmaxf(a[r], 0.0f);
                }
                if (res)  a += *(const f32x4*)&res[(size_t)m * N + nb];
                if (OUT_BF16) {
                    short4v pk;
                    #pragma unroll
                    for (int r = 0; r < 4; ++r) pk[r] = f2bf_bits(a[r]);
                    *(short4v*)&((bf16*)outp)[(size_t)m * N + nb] = pk;
                } else {
                    *(f32x4*)&((float*)outp)[(size_t)m * N + nb] = a;
                }
            }
        }
    }
}

// ---------------- 8-phase counted-vmcnt GEMM 256x256 (FFN1) ------------------
template<bool QKV, bool RELU, bool OUT_BF16>
__global__ __launch_bounds__(512, 2) void gemm8ph(const bf16* __restrict__ A,
                                                  const bf16* __restrict__ Bt,
                                                  const float* __restrict__ bias,
                                                  const float* __restrict__ res,
                                                  void* __restrict__ outp,
                                                  int N, int K)
{
    extern __shared__ __align__(16) char smem[];
    bf16* const As0 = (bf16*)smem;
    bf16* const As1 = As0 + 256 * 64;
    bf16* const Bs0 = As1 + 256 * 64;
    bf16* const Bs1 = Bs0 + 256 * 64;

    const int tid  = threadIdx.x;
    const int lane = tid & 63, wid = tid >> 6;
    const int l16  = lane & 15, quad = lane >> 4;
    const int wm   = wid >> 2, wn = wid & 3;

    const int gridx = gridDim.x;
    const int nwg   = gridx * gridDim.y;
    int bid = blockIdx.y * gridx + blockIdx.x;
    bid = (bid & 7) * (nwg >> 3) + (bid >> 3);            // bijective XCD swizzle
    const int tn = (bid % gridx) * 256;
    const int tm = (bid / gridx) * 256;
    const bool vblk = QKV && (tn >= 1024);
    const int NT = K >> 6, NI = NT >> 1;

    f32x4 acc[2][4][4];
    #pragma unroll
    for (int q = 0; q < 2; ++q)
        #pragma unroll
        for (int i = 0; i < 4; ++i)
            #pragma unroll
            for (int j = 0; j < 4; ++j) acc[q][i][j] = (f32x4){0.f, 0.f, 0.f, 0.f};

    bf16x8 af[4][2], bfr[4][2];

#define SA8(dst, u, h) do {                                                          \
    const int _k0 = (u) << 6;                                                        \
    _Pragma("unroll")                                                                \
    for (int _j = 0; _j < 2; ++_j) {                                                 \
        const int _g = (h) * 1024 + _j * 512 + tid;                                  \
        const int _r = _g >> 3, _p = _g & 7;                                         \
        const int _c = _p ^ (_r & 7);                                                \
        __builtin_amdgcn_global_load_lds((const AS_G void*)(A + (size_t)(tm + _r) * K + _k0 + _c * 8), \
                                         (AS_L void*)((dst) + _g * 8), 16, 0, 0);    \
    } } while (0)

#define SB8(dst, u, h) do {                                                          \
    const int _k0 = (u) << 6;                                                        \
    _Pragma("unroll")                                                                \
    for (int _j = 0; _j < 2; ++_j) {                                                 \
        const int _g = (h) * 1024 + _j * 512 + tid;                                  \
        const int _r = _g >> 3, _p = _g & 7;                                         \
        const int _c = _p ^ (_r & 7);                                                \
        __builtin_amdgcn_global_load_lds((const AS_G void*)(Bt + (size_t)(tn + _r) * K + _k0 + _c * 8), \
                                         (AS_L void*)((dst) + _g * 8), 16, 0, 0);    \
    } } while (0)

#define LDA8(Ab, qm) do {                                                            \
    _Pragma("unroll")                                                                \
    for (int _mf = 0; _mf < 4; ++_mf)                                                \
        _Pragma("unroll")                                                            \
        for (int _kh = 0; _kh < 2; ++_kh) {                                          \
            const int _r = wm * 128 + (qm) * 64 + _mf * 16 + l16;                    \
            const int _p = (_kh * 4 + quad) ^ (_r & 7);                              \
            af[_mf][_kh] = *(const bf16x8*)&(Ab)[_r * 64 + _p * 8];                  \
        } } while (0)

#define LDB8(Bb, qn) do {                                                            \
    _Pragma("unroll")                                                                \
    for (int _c2 = 0; _c2 < 2; ++_c2)                                                \
        _Pragma("unroll")                                                            \
        for (int _kh = 0; _kh < 2; ++_kh) {                                          \
            const int _nf = (qn) * 2 + _c2;                                          \
            const int _r = wn * 64 + _nf * 16 + l16;                                 \
            const int _p = (_kh * 4 + quad) ^ (_r & 7);                              \
            bfr[_nf][_kh] = *(const bf16x8*)&(Bb)[_r * 64 + _p * 8];                 \
        } } while (0)

#define MM8(qm, qn) do {                                                             \
    __builtin_amdgcn_s_setprio(1);                                                   \
    _Pragma("unroll")                                                                \
    for (int _mf = 0; _mf < 4; ++_mf)                                                \
        _Pragma("unroll")                                                            \
        for (int _c2 = 0; _c2 < 2; ++_c2) {                                          \
            const int _nf = (qn) * 2 + _c2;                                          \
            _Pragma("unroll")                                                        \
            for (int _kh = 0; _kh < 2; ++_kh) {                                      \
                if (vblk) acc[qm][_mf][_nf] = __builtin_amdgcn_mfma_f32_16x16x32_bf16(af[_mf][_kh], bfr[_nf][_kh], acc[qm][_mf][_nf], 0, 0, 0); \
                else      acc[qm][_mf][_nf] = __builtin_amdgcn_mfma_f32_16x16x32_bf16(bfr[_nf][_kh], af[_mf][_kh], acc[qm][_mf][_nf], 0, 0, 0); \
            }                                                                        \
        }                                                                            \
    __builtin_amdgcn_s_setprio(0);                                                   \
    } while (0)

#define GATE8() do { SCHED_FENCE(); __builtin_amdgcn_s_barrier();                    \
    asm volatile("s_waitcnt lgkmcnt(0)" ::: "memory"); SCHED_FENCE(); } while (0)
#define ENDP8() do { SCHED_FENCE(); __builtin_amdgcn_s_barrier(); SCHED_FENCE(); } while (0)

    SA8(As0, 0, 0); SA8(As0, 0, 1);
    SB8(Bs0, 0, 0); SB8(Bs0, 0, 1);
    SB8(Bs1, 1, 0); SB8(Bs1, 1, 1);
    asm volatile("s_waitcnt vmcnt(4)" ::: "memory");
    SCHED_FENCE();
    __builtin_amdgcn_s_barrier();
    SCHED_FENCE();

    for (int i = 0; i < NI; ++i) {
        const int t1 = 2 * i + 1, t2 = 2 * i + 2, t3 = 2 * i + 3;
        const bool p2 = t2 < NT, p3 = t3 < NT, lastI = (i == NI - 1);

        LDA8(As0, 0); LDB8(Bs0, 0);
        SA8(As1, t1, 0);
        GATE8(); MM8(0, 0); ENDP8();

        LDB8(Bs0, 1);
        SA8(As1, t1, 1);
        GATE8(); MM8(0, 1); ENDP8();

        LDA8(As0, 1);
        if (p2) SB8(Bs0, t2, 0);
        GATE8(); MM8(1, 1); ENDP8();

        if (p2) SA8(As0, t2, 0);
        if (lastI) asm volatile("s_waitcnt vmcnt(0)" ::: "memory");
        else       asm volatile("s_waitcnt vmcnt(4)" ::: "memory");
        GATE8(); MM8(1, 0); ENDP8();

        LDA8(As1, 0); LDB8(Bs1, 0);
        if (p2) SA8(As0, t2, 1);
        GATE8(); MM8(0, 0); ENDP8();

        LDB8(Bs1, 1);
        if (p2) SB8(Bs0, t2, 1);
        GATE8(); MM8(0, 1); ENDP8();

        LDA8(As1, 1);
        if (p3) SB8(Bs1, t3, 0);
        GATE8(); MM8(1, 1); ENDP8();

        if (p3) SB8(Bs1, t3, 1);
        if (lastI) asm volatile("s_waitcnt vmcnt(0)" ::: "memory");
        else       asm volatile("s_waitcnt vmcnt(4)" ::: "memory");
        GATE8(); MM8(1, 0); ENDP8();
    }

#undef SA8
#undef SB8
#undef LDA8
#undef LDB8
#undef MM8
#undef GATE8
#undef ENDP8

    // epilogue (non-QKV path used for FFN1)
    {
        #pragma unroll
        for (int qm = 0; qm < 2; ++qm)
            #pragma unroll
            for (int mf = 0; mf < 4; ++mf) {
                const int m = tm + wm * 128 + qm * 64 + mf * 16 + l16;
                #pragma unroll
                for (int nf = 0; nf < 4; ++nf) {
                    const int nb = tn + wn * 64 + nf * 16 + quad * 4;
                    f32x4 a = acc[qm][mf][nf];
                    if (bias) a += *(const f32x4*)&bias[nb];
                    if (RELU) {
                        #pragma unroll
                        for (int r = 0; r < 4; ++r) a[r] = fmaxf(a[r], 0.0f);
                    }
                    if (res)  a += *(const f32x4*)&res[(size_t)m * N + nb];
                    if (OUT_BF16) {
                        short4v pk;
                        #pragma unroll
                        for (int r = 0; r < 4; ++r) pk[r] = f2bf_bits(a[r]);
                        *(short4v*)&((bf16*)outp)[(size_t)m * N + nb] = pk;
                    } else {
                        *(f32x4*)&((float*)outp)[(size_t)m * N + nb] = a;
                    }
                }
            }
    }
}

// ---------------- 4-phase counted-vmcnt GEMM 256x128 (QKV + FFN2) ------------
// BM=256 BN=128 BK=64. 512 thr = 8 waves (2Mx4N), per-wave 128x32 =
// acc[qm][mf][nf(2)]. LDS 96 KB dyn: A[2][256x64] | B[2][128x64], XOR-8
// chunk swizzle. Buffer select by offset arithmetic (no LDS pointer arrays —
// they generate an unsupported addrspacecast static initializer).
//  phA: LDB(4)+LDA qm0(8); issue SA(t+1,q1)[2]; bar+lgk0; 16 MFMA; bar
//  phB: LDA qm1(8); issue SB(t+2)[2]+SA(t+2,q0)[2]; vmcnt(4); bar+lgk0;
//       16 MFMA; bar
template<bool QKV, bool RELU, bool OUT_BF16>
__global__ __launch_bounds__(512, 2) void gemm4ph(const bf16* __restrict__ A,
                                                  const bf16* __restrict__ Bt,
                                                  const float* __restrict__ bias,
                                                  const float* __restrict__ res,
                                                  void* __restrict__ outp,
                                                  int N, int K)
{
    extern __shared__ __align__(16) char smem[];
    bf16* const Asl = (bf16*)smem;                  // 2 x [256*64]
    bf16* const Bsl = Asl + 2 * 256 * 64;           // 2 x [128*64]

    const int tid  = threadIdx.x;
    const int lane = tid & 63, wid = tid >> 6;
    const int l16  = lane & 15, quad = lane >> 4;
    const int wm   = wid >> 2, wn = wid & 3;

    const int gridx = gridDim.x;
    const int nwg   = gridx * gridDim.y;
    int bid = blockIdx.y * gridx + blockIdx.x;
    bid = (bid & 7) * (nwg >> 3) + (bid >> 3);      // bijective XCD swizzle
    const int tn = (bid % gridx) * 128;
    const int tm = (bid / gridx) * 256;
    const bool vblk = QKV && (tn >= 1024);
    const int NT = K >> 6;

    f32x4 acc[2][4][2];
    #pragma unroll
    for (int q = 0; q < 2; ++q)
        #pragma unroll
        for (int i = 0; i < 4; ++i)
            #pragma unroll
            for (int j = 0; j < 2; ++j) acc[q][i][j] = (f32x4){0.f, 0.f, 0.f, 0.f};

    bf16x8 af[4][2], bfr[2][2];

// stage A rows-quadrant q (chunk groups {q, q+2} = rows {q*64..}u{q*64+128..})
// of K-tile u into buffer (u&1): 2 loads
#define SAQ4(u, q) do {                                                              \
    bf16* _dst = Asl + ((u) & 1) * (256 * 64);                                       \
    const int _k0 = (u) << 6;                                                        \
    _Pragma("unroll")                                                                \
    for (int _jj = 0; _jj < 2; ++_jj) {                                              \
        const int _g = ((q) + _jj * 2) * 512 + tid;                                  \
        const int _r = _g >> 3, _p = _g & 7;                                         \
        const int _c = _p ^ (_r & 7);                                                \
        __builtin_amdgcn_global_load_lds((const AS_G void*)(A + (size_t)(tm + _r) * K + _k0 + _c * 8), \
                                         (AS_L void*)(_dst + _g * 8), 16, 0, 0);     \
    } } while (0)

// stage full B tile of K-tile u into buffer (u&1): 2 loads
#define SB4(u) do {                                                                  \
    bf16* _dst = Bsl + ((u) & 1) * (128 * 64);                                       \
    const int _k0 = (u) << 6;                                                        \
    _Pragma("unroll")                                                                \
    for (int _jj = 0; _jj < 2; ++_jj) {                                              \
        const int _g = _jj * 512 + tid;                                              \
        const int _r = _g >> 3, _p = _g & 7;                                         \
        const int _c = _p ^ (_r & 7);                                                \
        __builtin_amdgcn_global_load_lds((const AS_G void*)(Bt + (size_t)(tn + _r) * K + _k0 + _c * 8), \
                                         (AS_L void*)(_dst + _g * 8), 16, 0, 0);     \
    } } while (0)

#define LDA4(Ab, qm) do {                                                            \
    _Pragma("unroll")                                                                \
    for (int _mf = 0; _mf < 4; ++_mf)                                                \
        _Pragma("unroll")                                                            \
        for (int _kh = 0; _kh < 2; ++_kh) {                                          \
            const int _r = wm * 128 + (qm) * 64 + _mf * 16 + l16;                    \
            const int _p = (_kh * 4 + quad) ^ (_r & 7);                              \
            af[_mf][_kh] = *(const bf16x8*)&(Ab)[_r * 64 + _p * 8];                  \
        } } while (0)

#define LDB4(Bb) do {                                                                \
    _Pragma("unroll")                                                                \
    for (int _nf = 0; _nf < 2; ++_nf)                                                \
        _Pragma("unroll")                                                            \
        for (int _kh = 0; _kh < 2; ++_kh) {                                          \
            const int _r = wn * 32 + _nf * 16 + l16;                                 \
            const int _p = (_kh * 4 + quad) ^ (_r & 7);                              \
            bfr[_nf][_kh] = *(const bf16x8*)&(Bb)[_r * 64 + _p * 8];                 \
        } } while (0)

#define MM4(qm) do {                                                                 \
    __builtin_amdgcn_s_setprio(1);                                                   \
    _Pragma("unroll")                                                                \
    for (int _mf = 0; _mf < 4; ++_mf)                                                \
        _Pragma("unroll")                                                            \
        for (int _nf = 0; _nf < 2; ++_nf)                                            \
            _Pragma("unroll")                                                        \
            for (int _kh = 0; _kh < 2; ++_kh) {                                      \
                if (vblk) acc[qm][_mf][_nf] = __builtin_amdgcn_mfma_f32_16x16x32_bf16(af[_mf][_kh], bfr[_nf][_kh], acc[qm][_mf][_nf], 0, 0, 0); \
                else      acc[qm][_mf][_nf] = __builtin_amdgcn_mfma_f32_16x16x32_bf16(bfr[_nf][_kh], af[_mf][_kh], acc[qm][_mf][_nf], 0, 0, 0); \
            }                                                                        \
    __builtin_amdgcn_s_setprio(0);                                                   \
    } while (0)

#define GATE4() do { SCHED_FENCE(); __builtin_amdgcn_s_barrier();                    \
    asm volatile("s_waitcnt lgkmcnt(0)" ::: "memory"); SCHED_FENCE(); } while (0)
#define ENDP4() do { SCHED_FENCE(); __builtin_amdgcn_s_barrier(); SCHED_FENCE(); } while (0)

    // Prologue: t0 full [6 loads]; t1: B + qm0-rows [4 loads]; vmcnt(4) -> t0
    // complete, t1's 4 in flight.
    SB4(0); SAQ4(0, 0); SAQ4(0, 1);
    if (NT > 1) { SB4(1); SAQ4(1, 0); }
    if (NT > 1) asm volatile("s_waitcnt vmcnt(4)" ::: "memory");
    else        asm volatile("s_waitcnt vmcnt(0)" ::: "memory");
    SCHED_FENCE();
    __builtin_amdgcn_s_barrier();
    SCHED_FENCE();

    for (int t = 0; t < NT; ++t) {
        bf16* const Ab = Asl + (t & 1) * (256 * 64);
        bf16* const Bb = Bsl + (t & 1) * (128 * 64);

        // ---- phA ----
        LDB4(Bb); LDA4(Ab, 0);
        if (t + 1 < NT) SAQ4(t + 1, 1);              // finish t+1's A
        GATE4(); MM4(0); ENDP4();

        // ---- phB ----
        LDA4(Ab, 1);
        if (t + 2 < NT) { SB4(t + 2); SAQ4(t + 2, 0); }
        if (t + 2 < NT) asm volatile("s_waitcnt vmcnt(4)" ::: "memory");
        else            asm volatile("s_waitcnt vmcnt(0)" ::: "memory");
        GATE4(); MM4(1); ENDP4();
    }

#undef SAQ4
#undef SB4
#undef LDA4
#undef LDB4
#undef MM4
#undef GATE4
#undef ENDP4

    // ---------------- epilogues ----------------
    if (QKV) {
        bf16* qkv = (bf16*)outp;                 // q base; k at +8M elems, v at +16M
        if (!vblk) {
            const int which = tn >> 9;           // 0=q, 1=k
            bf16* dst = qkv + (size_t)which * (8u << 20);
            #pragma unroll
            for (int qm = 0; qm < 2; ++qm)
                #pragma unroll
                for (int mf = 0; mf < 4; ++mf) {
                    const int m = tm + wm * 128 + qm * 64 + mf * 16 + l16;   // token
                    const int bb = m >> 9, t = m & 511;
                    #pragma unroll
                    for (int nf = 0; nf < 2; ++nf) {
                        const int nb = tn + wn * 32 + nf * 16 + quad * 4;
                        const int hh = (nb >> 6) & 7, dd = nb & 63;
                        short4v pk;
                        #pragma unroll
                        for (int r = 0; r < 4; ++r) pk[r] = f2bf_bits(acc[qm][mf][nf][r]);
                        *(short4v*)&dst[((size_t)(bb * 8 + hh) * 512 + t) * 64 + dd] = pk;
                    }
                }
        } else {
            bf16* dst = qkv + (size_t)2 * (8u << 20);
            #pragma unroll
            for (int qm = 0; qm < 2; ++qm)
                #pragma unroll
                for (int mf = 0; mf < 4; ++mf) {
                    const int mb = tm + wm * 128 + qm * 64 + mf * 16 + quad * 4;  // token base
                    const int bb = mb >> 9, t = mb & 511;
                    #pragma unroll
                    for (int nf = 0; nf < 2; ++nf) {
                        const int n = tn + wn * 32 + nf * 16 + l16;
                        const int hh = (n >> 6) & 7, dd = n & 63;
                        short4v pk;
                        #pragma unroll
                        for (int r = 0; r < 4; ++r) pk[r] = f2bf_bits(acc[qm][mf][nf][r]);
                        *(short4v*)&dst[((size_t)(bb * 8 + hh) * 64 + dd) * 512 + t] = pk;
                    }
                }
        }
    } else {
        #pragma unroll
        for (int qm = 0; qm < 2; ++qm)
            #pragma unroll
            for (int mf = 0; mf < 4; ++mf) {
                const int m = tm + wm * 128 + qm * 64 + mf * 16 + l16;
                #pragma unroll
                for (int nf = 0; nf < 2; ++nf) {
                    const int nb = tn + wn * 32 + nf * 16 + quad * 4;
                    f32x4 a = acc[qm][mf][nf];
                    if (bias) a += *(const f32x4*)&bias[nb];
                    if (RELU) {
                        #pragma unroll
                        for (int r = 0; r < 4; ++r) a[r] = fmaxf(a[r], 0.0f);
                    }
                    if (res)  a += *(const f32x4*)&res[(size_t)m * N + nb];
                    if (OUT_BF16) {
                        short4v pk;
                        #pragma unroll
                        for (int r = 0; r < 4; ++r) pk[r] = f2bf_bits(a[r]);
                        *(short4v*)&((bf16*)outp)[(size_t)m * N + nb] = pk;
                    } else {
                        *(f32x4*)&((float*)outp)[(size_t)m * N + nb] = a;
                    }
                }
            }
    }
}

// ---------------- Flash attention: qt-paired, dbuf global_load_lds -----------
#define ATTN_TILE(qa, m_i, l_i, Of, qw, qtT)                                          \
  do {                                                                                \
    f32x4 Sf[4];                                                                      \
    _Pragma("unroll")                                                                 \
    for (int kf = 0; kf < 4; ++kf) {                                                  \
        const int row = kf * 16 + l16;                                                \
        bf16x8 b0 = *(const bf16x8*)&Ks[cur][row * 64 + ((quad ^ (row & 7)) * 8)];    \
        bf16x8 b1 = *(const bf16x8*)&Ks[cur][row * 64 + (((4 + quad) ^ (row & 7)) * 8)]; \
        f32x4 z = (f32x4){0.f, 0.f, 0.f, 0.f};                                        \
        z = __builtin_amdgcn_mfma_f32_16x16x32_bf16(qa[0], b0, z, 0, 0, 0);           \
        z = __builtin_amdgcn_mfma_f32_16x16x32_bf16(qa[1], b1, z, 0, 0, 0);           \
        Sf[kf] = z;                                                                   \
    }                                                                                 \
    if (kt == qtT) {                                                                  \
        _Pragma("unroll")                                                             \
        for (int kf = 0; kf < 4; ++kf)                                                \
            _Pragma("unroll")                                                         \
            for (int r = 0; r < 4; ++r)                                               \
                if (kt * 64 + kf * 16 + l16 > (qw) + quad * 4 + r) Sf[kf][r] = -1e30f;\
    }                                                                                 \
    float mnew[4], alpha[4];                                                          \
    _Pragma("unroll")                                                                 \
    for (int r = 0; r < 4; ++r) {                                                     \
        float v = fmaxf(fmaxf(Sf[0][r], Sf[1][r]), fmaxf(Sf[2][r], Sf[3][r]));        \
        v = fmaxf(v, __shfl_xor(v, 1, 64));                                           \
        v = fmaxf(v, __shfl_xor(v, 2, 64));                                           \
        v = fmaxf(v, __shfl_xor(v, 4, 64));                                           \
        v = fmaxf(v, __shfl_xor(v, 8, 64));                                           \
        mnew[r]   = fmaxf(m_i[r], v);                                                 \
        alpha[r]  = __expf(m_i[r] - mnew[r]);                                         \
        m_i[r]    = mnew[r];                                                          \
    }                                                                                 \
    float rs[4] = {0.f, 0.f, 0.f, 0.f};                                               \
    _Pragma("unroll")                                                                 \
    for (int kf = 0; kf < 4; ++kf) {                                                  \
        _Pragma("unroll")                                                             \
        for (int r = 0; r < 4; ++r) {                                                 \
            float p = __expf(Sf[kf][r] - mnew[r]);                                    \
            rs[r] += p;                                                               \
            Pw[wave][quad * 4 + r][kf * 16 + l16] = f2bf(p);                          \
        }                                                                             \
    }                                                                                 \
    _Pragma("unroll")                                                                 \
    for (int r = 0; r < 4; ++r) {                                                     \
        rs[r] += __shfl_xor(rs[r], 1, 64);                                            \
        rs[r] += __shfl_xor(rs[r], 2, 64);                                            \
        rs[r] += __shfl_xor(rs[r], 4, 64);                                            \
        rs[r] += __shfl_xor(rs[r], 8, 64);                                            \
        l_i[r] = l_i[r] * alpha[r] + rs[r];                                           \
    }                                                                                 \
    _Pragma("unroll")                                                                 \
    for (int f = 0; f < 4; ++f)                                                       \
        _Pragma("unroll")                                                             \
        for (int r = 0; r < 4; ++r)                                                   \
            Of[f][r] *= alpha[r];                                                     \
    bf16x8 pa0 = *(const bf16x8*)&Pw[wave][l16][quad * 8];                            \
    bf16x8 pa1 = *(const bf16x8*)&Pw[wave][l16][32 + quad * 8];                       \
    _Pragma("unroll")                                                                 \
    for (int f = 0; f < 4; ++f) {                                                     \
        const int vrow = f * 16 + l16;                                                \
        bf16x8 vb0 = *(const bf16x8*)&Vt[cur][vrow * 64 + ((quad ^ (vrow & 7)) * 8)]; \
        bf16x8 vb1 = *(const bf16x8*)&Vt[cur][vrow * 64 + (((4 + quad) ^ (vrow & 7)) * 8)]; \
        Of[f] = __builtin_amdgcn_mfma_f32_16x16x32_bf16(pa0, vb0, Of[f], 0, 0, 0);    \
        Of[f] = __builtin_amdgcn_mfma_f32_16x16x32_bf16(pa1, vb1, Of[f], 0, 0, 0);    \
    }                                                                                 \
  } while (0)

__global__ __launch_bounds__(256, 2) void attn_kernel(const bf16* __restrict__ q,
                                                      const bf16* __restrict__ kM,
                                                      const bf16* __restrict__ vT,
                                                      bf16* __restrict__ o)
{
    __shared__ __align__(16) bf16 Ks[2][64 * 64];
    __shared__ __align__(16) bf16 Vt[2][64 * 64];
    __shared__ __align__(16) bf16 Pw[4][16][72];

    const int tid  = threadIdx.x;
    const int wave = tid >> 6, lane = tid & 63;
    const int l16  = lane & 15, quad = lane >> 4;

    const int nwg = gridDim.x * gridDim.y;
    int bid = blockIdx.y * gridDim.x + blockIdx.x;
    bid = (bid & 7) * (nwg >> 3) + (bid >> 3);
    const int pair = bid & 3;
    const int bh   = bid >> 2;

    const int qt0 = pair, qt1 = 7 - pair;
    const int qw0 = qt0 * 64 + wave * 16;
    const int qw1 = qt1 * 64 + wave * 16;

    const float scale = 0.04419417382415922f;  // C^-0.5 (reference uses n_embd)
    bf16x8 qa0[2], qa1[2];
    #pragma unroll
    for (int c = 0; c < 2; ++c) {
        bf16x8 t0 = *(const bf16x8*)(q + ((size_t)bh * T_ + qw0 + l16) * 64 + c * 32 + quad * 8);
        bf16x8 t1 = *(const bf16x8*)(q + ((size_t)bh * T_ + qw1 + l16) * 64 + c * 32 + quad * 8);
        #pragma unroll
        for (int j = 0; j < 8; ++j) {
            t0[j] = f2bf_bits(bfbits2f(t0[j]) * scale);
            t1[j] = f2bf_bits(bfbits2f(t1[j]) * scale);
        }
        qa0[c] = t0; qa1[c] = t1;
    }

    float m0[4], l0[4], m1[4], l1[4];
    f32x4 O0[4], O1[4];
    #pragma unroll
    for (int r = 0; r < 4; ++r) { m0[r] = -1e30f; l0[r] = 0.f; m1[r] = -1e30f; l1[r] = 0.f; }
    #pragma unroll
    for (int f = 0; f < 4; ++f) { O0[f] = (f32x4){0.f,0.f,0.f,0.f}; O1[f] = (f32x4){0.f,0.f,0.f,0.f}; }

    auto STAGE = [&](int buf, int kt) {
        const int k0 = kt * 64;
        #pragma unroll
        for (int j = 0; j < 2; ++j) {
            const int g = j * 256 + tid;
            const int row = g >> 3, phys = g & 7;
            const int c = phys ^ (row & 7);
            __builtin_amdgcn_global_load_lds((const AS_G void*)(kM + ((size_t)bh * T_ + k0 + row) * 64 + c * 8),
                                             (AS_L void*)&Ks[buf][(size_t)g * 8], 16, 0, 0);
            __builtin_amdgcn_global_load_lds((const AS_G void*)(vT + ((size_t)bh * 64 + row) * T_ + k0 + c * 8),
                                             (AS_L void*)&Vt[buf][(size_t)g * 8], 16, 0, 0);
        }
    };

    STAGE(0, 0);
    __syncthreads();

    int cur = 0;
    for (int kt = 0; kt <= qt1; ++kt) {
        if (kt < qt1) STAGE(cur ^ 1, kt + 1);

        if (kt <= qt0) ATTN_TILE(qa0, m0, l0, O0, qw0, qt0);
        ATTN_TILE(qa1, m1, l1, O1, qw1, qt1);

        __syncthreads();
        cur ^= 1;
    }

    const int b = bh >> 3, hh = bh & 7;
    #pragma unroll
    for (int r = 0; r < 4; ++r) {
        const float inv0 = 1.0f / l0[r];
        const float inv1 = 1.0f / l1[r];
        const int t0 = qw0 + quad * 4 + r;
        const int t1 = qw1 + quad * 4 + r;
        #pragma unroll
        for (int f = 0; f < 4; ++f) {
            o[((size_t)b * T_ + t0) * C_ + hh * 64 + f * 16 + l16] = f2bf(O0[f][r] * inv0);
            o[((size_t)b * T_ + t1) * C_ + hh * 64 + f * 16 + l16] = f2bf(O1[f][r] * inv1);
        }
    }
}

// -----------------------------------------------------------------------------
extern "C" void kernel_launch(void* const* d_in, const int* in_sizes, int n_in,
                              void* d_out, int out_size, void* d_ws, size_t ws_size,
                              hipStream_t stream)
{
    const float* x     = (const float*)d_in[0];
    const float* wq    = (const float*)d_in[1];
    const float* wk    = (const float*)d_in[2];
    const float* wv    = (const float*)d_in[3];
    const float* wproj = (const float*)d_in[4];
    const float* bproj = (const float*)d_in[5];
    const float* w1    = (const float*)d_in[6];
    const float* b1    = (const float*)d_in[7];
    const float* w2    = (const float*)d_in[8];
    const float* b2    = (const float*)d_in[9];
    const float* ln1g  = (const float*)d_in[10];
    const float* ln1b  = (const float*)d_in[11];
    const float* ln2g  = (const float*)d_in[12];
    const float* ln2b  = (const float*)d_in[13];

    char* ws = (char*)d_ws;
    bf16*  h    = (bf16*)(ws + 0);
    bf16*  q    = (bf16*)(ws + ((size_t)16 << 20));
    bf16*  k    = (bf16*)(ws + ((size_t)32 << 20));
    bf16*  v    = (bf16*)(ws + ((size_t)48 << 20));   // (B,H,D,T)
    bf16*  mid  = (bf16*)(ws + 0);
    bf16*  o    = (bf16*)(ws + ((size_t)64 << 20));
    bf16*  h2   = (bf16*)(ws + ((size_t)80 << 20));
    bf16*  wt   = (bf16*)(ws + ((size_t)96 << 20));
    bf16*  projt = wt + (size_t)1536 * 512;
    bf16*  w1t   = wt + (size_t)2048 * 512;
    bf16*  w2t   = wt + (size_t)4096 * 512;
    float* x1    = (float*)d_out;

    // allow big dynamic LDS on the pipelined GEMMs (one-time)
    static bool smem_init = false;
    if (!smem_init) {
        smem_init = true;
        (void)hipFuncSetAttribute(reinterpret_cast<const void*>(&gemm8ph<false, true,  true>),
                                  hipFuncAttributeMaxDynamicSharedMemorySize, 131072);
        (void)hipFuncSetAttribute(reinterpret_cast<const void*>(&gemm4ph<true,  false, true>),
                                  hipFuncAttributeMaxDynamicSharedMemorySize, 98304);
        (void)hipFuncSetAttribute(reinterpret_cast<const void*>(&gemm4ph<false, false, false>),
                                  hipFuncAttributeMaxDynamicSharedMemorySize, 98304);
    }

    // 0. all weight transposes (f32 -> bf16, [N][K])
    transpose_all<<<768, 256, 0, stream>>>(wq, wk, wv, wproj, w1, w2, wt);

    // 1. h = LN1(x)
    ln_kernel<<<BT, 256, 0, stream>>>(x, ln1g, ln1b, h);

    // 2. q|k|v = h @ wqkv  (one N=1536 GEMM); 4-phase, grid 768 = 3 exact waves
    gemm4ph<true,  false, true><<<dim3(12, 64), 512, 98304, stream>>>(h, wt, nullptr, nullptr, q, 1536, 512);

    // 3. o = flash-attn(q,k,v) -> (B,T,C); qt-paired grid
    attn_kernel<<<dim3(4, B_ * H_), 256, 0, stream>>>(q, k, v, o);

    // 4. x1 = x + o @ w_proj + b_proj   (x1 = d_out, f32); 2-phase 128^2
    mfma_gemm<false, false, false><<<dim3(4, 128), 256, 0, stream>>>(o, projt, bproj, x, x1, 512, 512);

    // 5. h2 = LN2(x1)
    ln_kernel<<<BT, 256, 0, stream>>>(x1, ln2g, ln2b, h2);

    // 6. mid = relu(h2 @ w1 + b1); 8-phase 256^2, grid 512 = 2 exact waves
    gemm8ph<false, true,  true><<<dim3(8, 64), 512, 131072, stream>>>(h2, w1t, b1, nullptr, mid, 2048, 512);

    // 7. out = x1 + mid @ w2 + b2 (in-place on d_out); 4-phase, grid 256 =
    //    1 exact wave, NT=32 deep pipeline
    gemm4ph<false, false, false><<<dim3(4, 64), 512, 98304, stream>>>(mid, w2t, b2, x1, (float*)d_out, 512, 2048);
}